// Round 1
// baseline (476.708 us; speedup 1.0000x reference)
//
#include <hip/hip_runtime.h>
#include <cstdint>
#include <cstddef>

// Causal self-attention. fp32 in / fp32 out. bf16 MFMA compute, fp32 accum.
// B=4 T=1024 C=2048 H=16 Dh=128.
//
// R9 = byte-identical resubmit of R8 (476.9 us verified): prior round's bench
// was an infra failure (container died twice, no counters). Re-establishing
// the baseline measurement + rocprof breakdown before the next structural
// change (candidate: 256^2 8-phase GEMM port if QKV gemm dominates).
//
// R8 attention: S^T = K.Q^T scalar-softmax (R7) + LDS staging via
// global_load_lds (R5/m97) + XOR-swizzle (chunk ^= row&7, applied on the
// per-lane GLOBAL source address since the LDS dst must be lane-contiguous)
// to kill the unpadded-row bank conflicts. Diagonal tt-skip. 2 barriers/iter.
// R7 lesson: direct-global MFMA operands serialize on VGPR-bound loads
// (~16K cyc/iter); async16's VGPR-free deep queue is the fix.

typedef __attribute__((ext_vector_type(8))) __bf16 bf16x8;
typedef __attribute__((ext_vector_type(4))) float f32x4;
typedef unsigned short u16;

#define NEG_BIG (-1.0e30f)

__device__ __forceinline__ u16 f2bf(float f) {
    union { float f; uint32_t u; } v; v.f = f;
    uint32_t r = v.u + 0x7FFFu + ((v.u >> 16) & 1u);   // RNE
    return (u16)(r >> 16);
}

__device__ __forceinline__ uint32_t pack2(float a, float b) {
    return (uint32_t)f2bf(a) | ((uint32_t)f2bf(b) << 16);
}

__device__ __forceinline__ f32x4 mfma16(bf16x8 a, bf16x8 b, f32x4 c) {
    return __builtin_amdgcn_mfma_f32_16x16x32_bf16(a, b, c, 0, 0, 0);
}

// async global->LDS, 16B/lane; LDS dst = wave-uniform base (+lane*16 by HW)
__device__ __forceinline__ void async16(const u16* g, u16* l) {
    __builtin_amdgcn_global_load_lds(
        (const __attribute__((address_space(1))) void*)g,
        (__attribute__((address_space(3))) void*)l, 16, 0, 0);
}

// ---------------------------------------------------------------------------
__global__ __launch_bounds__(256) void cvt_bf16(
    const float* __restrict__ x, u16* __restrict__ xb) {
    size_t i = ((size_t)blockIdx.x * 256 + threadIdx.x) * 8;
    float4 u = *(const float4*)(x + i);
    float4 v = *(const float4*)(x + i + 4);
    uint4 p;
    p.x = pack2(u.x, u.y); p.y = pack2(u.z, u.w);
    p.z = pack2(v.x, v.y); p.w = pack2(v.z, v.w);
    *(uint4*)(xb + i) = p;
}

// ---------------------------------------------------------------------------
__global__ __launch_bounds__(256) void transpose_w(
    const float* __restrict__ W, int ldW, u16* __restrict__ WT) {
    __shared__ u16 tile[64][68];
    const int n0 = blockIdx.x * 64, k0 = blockIdx.y * 64;
    const int t = threadIdx.x;
    for (int i = t; i < 4096; i += 256) {
        int r = i >> 6, c = i & 63;
        tile[r][c] = f2bf(W[(size_t)(k0 + r) * ldW + n0 + c]);
    }
    __syncthreads();
    for (int i = t; i < 4096; i += 256) {
        int r = i >> 6, c = i & 63;
        WT[(size_t)(n0 + r) * 2048 + k0 + c] = tile[c][r];
    }
}

// ---------------------------------------------------------------------------
// GEMM (unchanged from R6): C[M,N] = A[M,2048] @ Bt[N,2048].
// ---------------------------------------------------------------------------
__global__ __launch_bounds__(256) void gemm_k(
    const void* __restrict__ Av, const u16* __restrict__ Bt,
    int N, int amode, int omode,
    float* __restrict__ outf, u16* __restrict__ Qo, u16* __restrict__ Ko,
    u16* __restrict__ Vt) {
    const int K = 2048;
    __shared__ u16 As[128][32];
    __shared__ u16 Bs[128][32];

    const float* A32 = (const float*)Av;
    const u16*   A16 = (const u16*)Av;

    const int m0 = blockIdx.y * 128, n0 = blockIdx.x * 128;
    const int t = threadIdx.x;
    const int w = t >> 6, lane = t & 63;
    const int col = lane & 15, quad = lane >> 4;
    const int wrow = (w >> 1) * 64, wcol = (w & 1) * 64;

    f32x4 acc[4][4];
    #pragma unroll
    for (int i = 0; i < 4; ++i)
        #pragma unroll
        for (int j = 0; j < 4; ++j)
            acc[i][j] = (f32x4){0.f, 0.f, 0.f, 0.f};

    u16* as_flat = &As[0][0];
    u16* bs_flat = &Bs[0][0];
    const int c1 = (w << 6) | lane;
    const int c2 = c1 + 256;

    for (int k0 = 0; k0 < K; k0 += 32) {
        {
            const u16* g1 = Bt + (size_t)(n0 + (c1 >> 2)) * K + k0 + ((c1 & 3) << 3);
            async16(g1, bs_flat + (size_t)w * 512);
            const u16* g2 = Bt + (size_t)(n0 + (c2 >> 2)) * K + k0 + ((c2 & 3) << 3);
            async16(g2, bs_flat + 2048 + (size_t)w * 512);
        }
        if (amode == 2) {
            const u16* g1 = A16 + (size_t)(m0 + (c1 >> 2)) * K + k0 + ((c1 & 3) << 3);
            async16(g1, as_flat + (size_t)w * 512);
            const u16* g2 = A16 + (size_t)(m0 + (c2 >> 2)) * K + k0 + ((c2 & 3) << 3);
            async16(g2, as_flat + 2048 + (size_t)w * 512);
        } else if (amode == 1) {
            #pragma unroll
            for (int cc = 0; cc < 2; ++cc) {
                int c = cc ? c2 : c1;
                int r = c >> 2, ko = (c & 3) << 3;
                int kg = k0 + ko, h = kg >> 7, d = kg & 127;
                int m = m0 + r, b = m >> 10, tt = m & 1023;
                const u16* g = A16 + (((size_t)(b * 16 + h)) * 1024 + tt) * 128 + d;
                async16(g, as_flat + (size_t)(cc ? 2048 : 0) + (size_t)w * 512);
            }
        } else if (amode == 0) {
            #pragma unroll
            for (int c = t; c < 512; c += 256) {
                int r = c >> 2, ko = (c & 3) * 8;
                size_t off = (size_t)(m0 + r) * K + k0 + ko;
                float4 u = *(const float4*)(A32 + off);
                float4 v = *(const float4*)(A32 + off + 4);
                uint4 p;
                p.x = pack2(u.x, u.y); p.y = pack2(u.z, u.w);
                p.z = pack2(v.x, v.y); p.w = pack2(v.z, v.w);
                *(uint4*)&As[r][ko] = p;
            }
        } else {
            #pragma unroll
            for (int c = t; c < 512; c += 256) {
                int r = c >> 2, ko = (c & 3) * 8;
                int kg = k0 + ko, h = kg >> 7, d = kg & 127;
                int m = m0 + r, b = m >> 10, tt = m & 1023;
                *(uint4*)&As[r][ko] =
                    *(const uint4*)(A16 + (((size_t)(b * 16 + h)) * 1024 + tt) * 128 + d);
            }
        }
        __syncthreads();

        bf16x8 afr[4], bfr[4];
        #pragma unroll
        for (int i = 0; i < 4; ++i)
            afr[i] = *(const bf16x8*)&As[wrow + i * 16 + col][quad * 8];
        #pragma unroll
        for (int i = 0; i < 4; ++i)
            bfr[i] = *(const bf16x8*)&Bs[wcol + i * 16 + col][quad * 8];

        #pragma unroll
        for (int mt = 0; mt < 4; ++mt)
            #pragma unroll
            for (int nt = 0; nt < 4; ++nt)
                acc[mt][nt] = mfma16(afr[mt], bfr[nt], acc[mt][nt]);
        __syncthreads();
    }

    #pragma unroll
    for (int mt = 0; mt < 4; ++mt) {
        #pragma unroll
        for (int nt = 0; nt < 4; ++nt) {
            #pragma unroll
            for (int r = 0; r < 4; ++r) {
                int gm = m0 + wrow + mt * 16 + quad * 4 + r;
                int gn = n0 + wcol + nt * 16 + col;
                if (omode == 0) {
                    outf[(size_t)gm * N + gn] = acc[mt][nt][r];
                } else {
                    u16 bv = f2bf(acc[mt][nt][r]);
                    int b = gm >> 10, tq = gm & 1023;
                    if (omode == 3) {
                        int which = gn >> 11, rem = gn & 2047;
                        int h = rem >> 7, d = rem & 127;
                        size_t bh = (size_t)b * 16 + h;
                        if (which == 0)      Qo[(bh * 1024 + tq) * 128 + d] = bv;
                        else if (which == 1) Ko[(bh * 1024 + tq) * 128 + d] = bv;
                        else                 Vt[(bh * 128 + d) * 1024 + tq] = bv;
                    } else {
                        int h = gn >> 7, d = gn & 127;
                        size_t bh = (size_t)b * 16 + h;
                        if (omode == 1) Qo[(bh * 1024 + tq) * 128 + d] = bv;
                        else            Vt[(bh * 128 + d) * 1024 + tq] = bv;
                    }
                }
            }
        }
    }
}

// ---------------------------------------------------------------------------
// Flash attention R8. Grid (T/64, H, B), 256 threads = 4 waves, 16 q/wave.
// K tile [64][128] and V^T tile [128][64] staged via async16 with XOR-swizzle
// (LDS chunk (r,c) holds global chunk c^(r&7)); frag reads apply the same XOR
// -> bank pattern equals the proven GEMM LDS pattern. S^T formulation:
// lane holds S^T[t=tt*16+quad*4+r][q=col]; m/l/alpha scalar, 2-stage shuffle.
// Ps wave-private (barrier-free). O overwrites Q in place.
// ---------------------------------------------------------------------------
__global__ __launch_bounds__(256) void attn_kernel(
    u16* __restrict__ Q, const u16* __restrict__ K,
    const u16* __restrict__ VT) {
    __shared__ u16 Ks[64 * 128];     // swizzled, unpadded (async16 dst)
    __shared__ u16 Vs[128 * 64];     // swizzled, unpadded
    __shared__ u16 Ps[4][16][68];    // wave-private, padded (normal ds_write)

    const int qb = (int)(gridDim.x - 1) - (int)blockIdx.x;   // heavy first
    const int h = blockIdx.y, b = blockIdx.z;
    const int t = threadIdx.x;
    const int w = t >> 6, lane = t & 63;
    const int col = lane & 15, quad = lane >> 4;
    const int sw = col & 7;                       // read-side swizzle key
    const size_t bh = (size_t)b * 16 + h;
    u16* Qb = Q + bh * (1024 * 128);
    const u16* Kb = K + bh * (1024 * 128);
    const u16* Vb = VT + bh * (128 * 1024);
    const int q_lane = qb * 64 + w * 16 + col;

    // Q fragment, B-operand: lane holds Q[q=col][dh=kq*32+quad*8+j]
    bf16x8 qf[4];
    {
        const u16* qp = Qb + (size_t)q_lane * 128 + quad * 8;
        #pragma unroll
        for (int kq = 0; kq < 4; ++kq)
            qf[kq] = *(const bf16x8*)(qp + kq * 32);
    }

    f32x4 o[8];
    #pragma unroll
    for (int i = 0; i < 8; ++i) o[i] = (f32x4){0.f, 0.f, 0.f, 0.f};
    float m = NEG_BIG, l = 0.f;
    const float scale = 0.08838834764831845f;  // 1/sqrt(128)

    for (int kt = 0; kt <= qb; ++kt) {
        const u16* Kt = Kb + (size_t)kt * (64 * 128);

        // ---- stage K (64x128) + V^T (128x64) via swizzled async16 ----
        #pragma unroll
        for (int i = 0; i < 4; ++i) {
            int s = i * 256 + w * 64 + lane;          // chunk slot incl. lane
            int kr = s >> 4, kc = s & 15;             // K: 16 chunks/row
            async16(Kt + (size_t)kr * 128 + ((kc ^ (kr & 7)) << 3),
                    Ks + (size_t)(i * 256 + w * 64) * 8);
            int vr = s >> 3, vc = s & 7;              // V: 8 chunks/row
            async16(Vb + (size_t)vr * 1024 + kt * 64 + ((vc ^ (vr & 7)) << 3),
                    Vs + (size_t)(i * 256 + w * 64) * 8);
        }
        __syncthreads();

        // ---- S^T = K.Q^T ----
        const bool need_mask = (kt == qb);
        const int ttmax = need_mask ? w : 3;          // skip fully-masked strips
        f32x4 s[4];
        #pragma unroll
        for (int tt = 0; tt < 4; ++tt) {
            if (tt > ttmax) { s[tt] = (f32x4){NEG_BIG, NEG_BIG, NEG_BIG, NEG_BIG}; continue; }
            const u16* kbase = Ks + (size_t)(tt * 16 + col) * 128;
            f32x4 a = (f32x4){0.f, 0.f, 0.f, 0.f};
            #pragma unroll
            for (int kq = 0; kq < 4; ++kq)
                a = mfma16(*(const bf16x8*)(kbase + (((kq * 4 + quad) ^ sw) << 3)),
                           qf[kq], a);
            s[tt] = a;
        }

        // ---- scale + mask + max ----
        float rmax = NEG_BIG;
        #pragma unroll
        for (int tt = 0; tt < 4; ++tt) {
            if (tt > ttmax) continue;
            #pragma unroll
            for (int r = 0; r < 4; ++r) {
                float v = s[tt][r] * scale;
                int tg = kt * 64 + tt * 16 + quad * 4 + r;
                if (need_mask && tg > q_lane) v = NEG_BIG;
                s[tt][r] = v;
                rmax = fmaxf(rmax, v);
            }
        }
        rmax = fmaxf(rmax, __shfl_xor(rmax, 16, 64));
        rmax = fmaxf(rmax, __shfl_xor(rmax, 32, 64));

        float mnew = fmaxf(m, rmax);
        float alpha = __expf(m - mnew);
        m = mnew;

        // ---- P = exp(S^T - m) -> Ps[w][q][t] ----
        float rsum = 0.f;
        #pragma unroll
        for (int tt = 0; tt < 4; ++tt) {
            uint32_t* dst = (uint32_t*)&Ps[w][col][tt * 16 + quad * 4];
            if (tt > ttmax) { dst[0] = 0u; dst[1] = 0u; continue; }
            float p0 = __expf(s[tt][0] - mnew);
            float p1 = __expf(s[tt][1] - mnew);
            float p2 = __expf(s[tt][2] - mnew);
            float p3 = __expf(s[tt][3] - mnew);
            rsum += (p0 + p1) + (p2 + p3);
            dst[0] = pack2(p0, p1);
            dst[1] = pack2(p2, p3);
        }
        rsum += __shfl_xor(rsum, 16, 64);
        rsum += __shfl_xor(rsum, 32, 64);
        l = l * alpha + rsum;

        #pragma unroll
        for (int dt = 0; dt < 8; ++dt)
            #pragma unroll
            for (int r = 0; r < 4; ++r) o[dt][r] *= alpha;

        // ---- O^T += V^T.P^T ----
        #pragma unroll
        for (int ks = 0; ks < 2; ++ks) {
            bf16x8 pf = *(const bf16x8*)&Ps[w][col][ks * 32 + quad * 8];
            #pragma unroll
            for (int dt = 0; dt < 8; ++dt) {
                const u16* vbase = Vs + (size_t)(dt * 16 + col) * 64;
                o[dt] = mfma16(*(const bf16x8*)(vbase + (((ks * 4 + quad) ^ sw) << 3)),
                               pf, o[dt]);
            }
        }
        __syncthreads();   // all waves done reading before next overwrite
    }

    // epilogue: lane holds O^T[d=dt*16+quad*4+r][q=col]; 8B packed stores
    float inv = 1.0f / l;
    #pragma unroll
    for (int dt = 0; dt < 8; ++dt) {
        uint2 p;
        p.x = pack2(o[dt][0] * inv, o[dt][1] * inv);
        p.y = pack2(o[dt][2] * inv, o[dt][3] * inv);
        *(uint2*)&Qb[(size_t)q_lane * 128 + dt * 16 + quad * 4] = p;
    }
}

// ---------------------------------------------------------------------------
extern "C" void kernel_launch(void* const* d_in, const int* in_sizes, int n_in,
                              void* d_out, int out_size, void* d_ws, size_t ws_size,
                              hipStream_t stream) {
    const float* x      = (const float*)d_in[0];   // [4096, 2048]
    const float* w_qkv  = (const float*)d_in[1];   // [2048, 6144]
    const float* w_proj = (const float*)d_in[2];   // [2048, 2048]
    float* out = (float*)d_out;                    // [4096, 2048]

    const size_t SEG = (size_t)4 * 16 * 1024 * 128;      // 8,388,608 elems
    const size_t NEED_FAST = ((size_t)6144 * 2048 + SEG * 4) * 2;  // 92.3 MB

    if (ws_size >= NEED_FAST + (1u << 20)) {
        u16* wT = (u16*)d_ws;                 // 6144*2048, reused for proj
        u16* xb = wT + (size_t)6144 * 2048;
        u16* Qb = xb + SEG;
        u16* Kb = Qb + SEG;
        u16* Vb = Kb + SEG;

        cvt_bf16<<<4096, 256, 0, stream>>>(x, xb);
        transpose_w<<<dim3(96, 32), 256, 0, stream>>>(w_qkv, 6144, wT);

        gemm_k<<<dim3(48, 32), 256, 0, stream>>>(xb, wT, 6144, 2, 3,
                                                 nullptr, Qb, Kb, Vb);

        attn_kernel<<<dim3(16, 16, 4), 256, 0, stream>>>(Qb, Kb, Vb);

        transpose_w<<<dim3(32, 32), 256, 0, stream>>>(w_proj, 2048, wT);
        gemm_k<<<dim3(16, 32), 256, 0, stream>>>(Qb, wT, 2048, 1, 0,
                                                 out, nullptr, nullptr, nullptr);
    } else {
        // fallback (ws >= 58.7 MB), R5-proven sequence
        u16* wT = (u16*)d_ws;
        u16* Qb = wT + (size_t)2048 * 2048;
        u16* Kb = Qb + SEG;
        u16* Vb = Kb + SEG;

        transpose_w<<<dim3(32, 32), 256, 0, stream>>>(w_qkv + 0, 6144, wT);
        gemm_k<<<dim3(16, 32), 256, 0, stream>>>(x, wT, 2048, 0, 1,
                                                 nullptr, Qb, nullptr, nullptr);
        transpose_w<<<dim3(32, 32), 256, 0, stream>>>(w_qkv + 2048, 6144, wT);
        gemm_k<<<dim3(16, 32), 256, 0, stream>>>(x, wT, 2048, 0, 1,
                                                 nullptr, Kb, nullptr, nullptr);
        transpose_w<<<dim3(32, 32), 256, 0, stream>>>(w_qkv + 4096, 6144, wT);
        gemm_k<<<dim3(16, 32), 256, 0, stream>>>(x, wT, 2048, 0, 2,
                                                 nullptr, nullptr, nullptr, Vb);

        attn_kernel<<<dim3(16, 16, 4), 256, 0, stream>>>(Qb, Kb, Vb);

        transpose_w<<<dim3(32, 32), 256, 0, stream>>>(w_proj, 2048, wT);
        gemm_k<<<dim3(16, 32), 256, 0, stream>>>(Qb, wT, 2048, 3, 0,
                                                 out, nullptr, nullptr, nullptr);
    }
}

// Round 2
// 475.311 us; speedup vs baseline: 1.0029x; 1.0029x over previous
//
#include <hip/hip_runtime.h>
#include <cstdint>
#include <cstddef>

// Causal self-attention. fp32 in / fp32 out. bf16 MFMA compute, fp32 accum.
// B=4 T=1024 C=2048 H=16 Dh=128.
//
// R10: replace the two big GEMMs with a 256x256-tile BK=64 8-wave 8-phase
// counted-vmcnt kernel (m201 template, T2+T3+T4+T5). R9 counters: QKV gemm
// 184.7us @ MfmaUtil 24%, bank-conflict 1.26e7, HBM 11% -> 2-phase structural
// stall, not memory. Schedule: phases consume half-tiles {A0,B0},B1,A1,B0re;
// stages issue one half-tile/phase one tile ahead (order A0,B0,B1,A1);
// vmcnt(4) at P1-P3 retires exactly the needed half-tile (in-order vmcnt,
// m135); raw s_barrier + asm waits (no __syncthreads drain); chunk^=(row&7)
// swizzle via pre-swizzled global src + swizzled ds_read (rule 21).
//
// R8 attention unchanged: S^T = K.Q^T scalar-softmax, async16 staging with
// XOR-swizzle, diagonal tt-skip, 2 barriers/iter.

typedef __attribute__((ext_vector_type(8))) __bf16 bf16x8;
typedef __attribute__((ext_vector_type(4))) float f32x4;
typedef unsigned short u16;

#define NEG_BIG (-1.0e30f)

__device__ __forceinline__ u16 f2bf(float f) {
    union { float f; uint32_t u; } v; v.f = f;
    uint32_t r = v.u + 0x7FFFu + ((v.u >> 16) & 1u);   // RNE
    return (u16)(r >> 16);
}

__device__ __forceinline__ uint32_t pack2(float a, float b) {
    return (uint32_t)f2bf(a) | ((uint32_t)f2bf(b) << 16);
}

__device__ __forceinline__ f32x4 mfma16(bf16x8 a, bf16x8 b, f32x4 c) {
    return __builtin_amdgcn_mfma_f32_16x16x32_bf16(a, b, c, 0, 0, 0);
}

// async global->LDS, 16B/lane; LDS dst = wave-uniform base (+lane*16 by HW)
__device__ __forceinline__ void async16(const u16* g, u16* l) {
    __builtin_amdgcn_global_load_lds(
        (const __attribute__((address_space(1))) void*)g,
        (__attribute__((address_space(3))) void*)l, 16, 0, 0);
}

// ---------------------------------------------------------------------------
__global__ __launch_bounds__(256) void cvt_bf16(
    const float* __restrict__ x, u16* __restrict__ xb) {
    size_t i = ((size_t)blockIdx.x * 256 + threadIdx.x) * 8;
    float4 u = *(const float4*)(x + i);
    float4 v = *(const float4*)(x + i + 4);
    uint4 p;
    p.x = pack2(u.x, u.y); p.y = pack2(u.z, u.w);
    p.z = pack2(v.x, v.y); p.w = pack2(v.z, v.w);
    *(uint4*)(xb + i) = p;
}

// ---------------------------------------------------------------------------
__global__ __launch_bounds__(256) void transpose_w(
    const float* __restrict__ W, int ldW, u16* __restrict__ WT) {
    __shared__ u16 tile[64][68];
    const int n0 = blockIdx.x * 64, k0 = blockIdx.y * 64;
    const int t = threadIdx.x;
    for (int i = t; i < 4096; i += 256) {
        int r = i >> 6, c = i & 63;
        tile[r][c] = f2bf(W[(size_t)(k0 + r) * ldW + n0 + c]);
    }
    __syncthreads();
    for (int i = t; i < 4096; i += 256) {
        int r = i >> 6, c = i & 63;
        WT[(size_t)(n0 + r) * 2048 + k0 + c] = tile[c][r];
    }
}

// ---------------------------------------------------------------------------
// Old 128x128 GEMM kept for the small-workspace fallback path (fp32 A).
// ---------------------------------------------------------------------------
__global__ __launch_bounds__(256) void gemm_k(
    const void* __restrict__ Av, const u16* __restrict__ Bt,
    int N, int amode, int omode,
    float* __restrict__ outf, u16* __restrict__ Qo, u16* __restrict__ Ko,
    u16* __restrict__ Vt) {
    const int K = 2048;
    __shared__ u16 As[128][32];
    __shared__ u16 Bs[128][32];

    const float* A32 = (const float*)Av;
    const u16*   A16 = (const u16*)Av;

    const int m0 = blockIdx.y * 128, n0 = blockIdx.x * 128;
    const int t = threadIdx.x;
    const int w = t >> 6, lane = t & 63;
    const int col = lane & 15, quad = lane >> 4;
    const int wrow = (w >> 1) * 64, wcol = (w & 1) * 64;

    f32x4 acc[4][4];
    #pragma unroll
    for (int i = 0; i < 4; ++i)
        #pragma unroll
        for (int j = 0; j < 4; ++j)
            acc[i][j] = (f32x4){0.f, 0.f, 0.f, 0.f};

    u16* as_flat = &As[0][0];
    u16* bs_flat = &Bs[0][0];
    const int c1 = (w << 6) | lane;
    const int c2 = c1 + 256;

    for (int k0 = 0; k0 < K; k0 += 32) {
        {
            const u16* g1 = Bt + (size_t)(n0 + (c1 >> 2)) * K + k0 + ((c1 & 3) << 3);
            async16(g1, bs_flat + (size_t)w * 512);
            const u16* g2 = Bt + (size_t)(n0 + (c2 >> 2)) * K + k0 + ((c2 & 3) << 3);
            async16(g2, bs_flat + 2048 + (size_t)w * 512);
        }
        if (amode == 2) {
            const u16* g1 = A16 + (size_t)(m0 + (c1 >> 2)) * K + k0 + ((c1 & 3) << 3);
            async16(g1, as_flat + (size_t)w * 512);
            const u16* g2 = A16 + (size_t)(m0 + (c2 >> 2)) * K + k0 + ((c2 & 3) << 3);
            async16(g2, as_flat + 2048 + (size_t)w * 512);
        } else if (amode == 1) {
            #pragma unroll
            for (int cc = 0; cc < 2; ++cc) {
                int c = cc ? c2 : c1;
                int r = c >> 2, ko = (c & 3) << 3;
                int kg = k0 + ko, h = kg >> 7, d = kg & 127;
                int m = m0 + r, b = m >> 10, tt = m & 1023;
                const u16* g = A16 + (((size_t)(b * 16 + h)) * 1024 + tt) * 128 + d;
                async16(g, as_flat + (size_t)(cc ? 2048 : 0) + (size_t)w * 512);
            }
        } else if (amode == 0) {
            #pragma unroll
            for (int c = t; c < 512; c += 256) {
                int r = c >> 2, ko = (c & 3) * 8;
                size_t off = (size_t)(m0 + r) * K + k0 + ko;
                float4 u = *(const float4*)(A32 + off);
                float4 v = *(const float4*)(A32 + off + 4);
                uint4 p;
                p.x = pack2(u.x, u.y); p.y = pack2(u.z, u.w);
                p.z = pack2(v.x, v.y); p.w = pack2(v.z, v.w);
                *(uint4*)&As[r][ko] = p;
            }
        } else {
            #pragma unroll
            for (int c = t; c < 512; c += 256) {
                int r = c >> 2, ko = (c & 3) * 8;
                int kg = k0 + ko, h = kg >> 7, d = kg & 127;
                int m = m0 + r, b = m >> 10, tt = m & 1023;
                *(uint4*)&As[r][ko] =
                    *(const uint4*)(A16 + (((size_t)(b * 16 + h)) * 1024 + tt) * 128 + d);
            }
        }
        __syncthreads();

        bf16x8 afr[4], bfr[4];
        #pragma unroll
        for (int i = 0; i < 4; ++i)
            afr[i] = *(const bf16x8*)&As[wrow + i * 16 + col][quad * 8];
        #pragma unroll
        for (int i = 0; i < 4; ++i)
            bfr[i] = *(const bf16x8*)&Bs[wcol + i * 16 + col][quad * 8];

        #pragma unroll
        for (int mt = 0; mt < 4; ++mt)
            #pragma unroll
            for (int nt = 0; nt < 4; ++nt)
                acc[mt][nt] = mfma16(afr[mt], bfr[nt], acc[mt][nt]);
        __syncthreads();
    }

    #pragma unroll
    for (int mt = 0; mt < 4; ++mt) {
        #pragma unroll
        for (int nt = 0; nt < 4; ++nt) {
            #pragma unroll
            for (int r = 0; r < 4; ++r) {
                int gm = m0 + wrow + mt * 16 + quad * 4 + r;
                int gn = n0 + wcol + nt * 16 + col;
                if (omode == 0) {
                    outf[(size_t)gm * N + gn] = acc[mt][nt][r];
                } else {
                    u16 bv = f2bf(acc[mt][nt][r]);
                    int b = gm >> 10, tq = gm & 1023;
                    if (omode == 3) {
                        int which = gn >> 11, rem = gn & 2047;
                        int h = rem >> 7, d = rem & 127;
                        size_t bh = (size_t)b * 16 + h;
                        if (which == 0)      Qo[(bh * 1024 + tq) * 128 + d] = bv;
                        else if (which == 1) Ko[(bh * 1024 + tq) * 128 + d] = bv;
                        else                 Vt[(bh * 128 + d) * 1024 + tq] = bv;
                    } else {
                        int h = gn >> 7, d = gn & 127;
                        size_t bh = (size_t)b * 16 + h;
                        if (omode == 1) Qo[(bh * 1024 + tq) * 128 + d] = bv;
                        else            Vt[(bh * 128 + d) * 1024 + tq] = bv;
                    }
                }
            }
        }
    }
}

// ---------------------------------------------------------------------------
// R10 256x256 8-phase GEMM. 512 threads = 8 waves (2 wr x 4 wc), BK=64,
// double-buffered LDS (128 KiB). AMODE 2: A = bf16 [M][2048] row-major.
// AMODE 1: A = bf16 (b,h,t,d). OMODE 0: f32 out [M][N]. OMODE 3: QKV scatter.
//
// Swizzle: 16B chunk c of row r stored at chunk c^(r&7); staging reads the
// inverse-swizzled global chunk so LDS dst stays linear (global_load_lds
// requirement); ds_read applies the same XOR -> 2-way banks (free, m136).
//
// Wave fragment mapping (interleaved so phase reads hit one half-tile for
// ALL waves): A rows = mrep*32 + wr*16 + col; B rows = nrep*64 + wc*16 + col.
// Phase ds-read consumption: P1:{A0,B0} P2:{B1} P3:{A1} P4:{B0 re-read}.
// Stage issue (next tile):   P1: A0    P2: B0   P3: B1   P4: A1.
// vmcnt(4) at P1/P2/P3 retires exactly the half-tile the phase needs
// (in-order retirement, m135); no wait at P4; never drains to 0 (T4).
// ---------------------------------------------------------------------------
__device__ __forceinline__ bf16x8 ldsfrag(const u16* buf, int row, int ksl, int quad) {
    return *(const bf16x8*)(buf + (size_t)row * 64 +
                            ((((ksl << 2) | quad) ^ (row & 7)) << 3));
}

template<int AMODE>
__device__ __forceinline__ void stageA(
    u16* halfb, const u16* A, int m0h, int k0, int w, int lane) {
    #pragma unroll
    for (int j = 0; j < 2; ++j) {
        int s0 = (j << 9) | (w << 6);
        int s = s0 + lane;
        int r = s >> 3;
        int gc = (s & 7) ^ (r & 7);
        int k = k0 + (gc << 3);
        const u16* src;
        if constexpr (AMODE == 2) {
            src = A + (size_t)(m0h + r) * 2048 + k;
        } else {
            int m = m0h + r, b = m >> 10, tt = m & 1023;
            int hh = k >> 7, d = k & 127;
            src = A + (((size_t)(b * 16 + hh)) * 1024 + tt) * 128 + d;
        }
        async16(src, halfb + (size_t)s0 * 8);
    }
}

__device__ __forceinline__ void stageB256(
    u16* halfb, const u16* Bt, int n0h, int k0, int w, int lane) {
    #pragma unroll
    for (int j = 0; j < 2; ++j) {
        int s0 = (j << 9) | (w << 6);
        int s = s0 + lane;
        int r = s >> 3;
        int gc = (s & 7) ^ (r & 7);
        async16(Bt + (size_t)(n0h + r) * 2048 + k0 + (gc << 3),
                halfb + (size_t)s0 * 8);
    }
}

template<int AMODE, int OMODE>
__global__ __launch_bounds__(512, 2) void gemm256(
    const u16* __restrict__ A, const u16* __restrict__ Bt, int N,
    float* __restrict__ outf, u16* __restrict__ Qo, u16* __restrict__ Ko,
    u16* __restrict__ Vt) {
    __shared__ u16 As[2][256 * 64];
    __shared__ u16 Bs[2][256 * 64];

    const int m0 = blockIdx.y * 256, n0 = blockIdx.x * 256;
    const int t = threadIdx.x;
    const int w = t >> 6, lane = t & 63;
    const int col = lane & 15, quad = lane >> 4;
    const int wr16 = ((w >> 2) & 1) << 4;   // 0 or 16
    const int wc16 = (w & 3) << 4;          // 0,16,32,48

    f32x4 acc[8][4];
    #pragma unroll
    for (int i = 0; i < 8; ++i)
        #pragma unroll
        for (int j = 0; j < 4; ++j)
            acc[i][j] = (f32x4){0.f, 0.f, 0.f, 0.f};

    // prologue: tile 0 -> buf0, issue order A0, B0, B1, A1
    stageA<AMODE>(As[0],             A,  m0,       0, w, lane);
    stageB256(    Bs[0],             Bt, n0,       0, w, lane);
    stageB256(    Bs[0] + 128 * 64,  Bt, n0 + 128, 0, w, lane);
    stageA<AMODE>(As[0] + 128 * 64,  A,  m0 + 128, 0, w, lane);

    const int NT = 2048 / 64;   // 32
    bf16x8 a_frag[8], b_frag[4];

    for (int kt = 0; kt < NT; ++kt) {
        const int bt = kt & 1, bn = bt ^ 1;
        const int ktn = (kt + 1 < NT) ? kt + 1 : 0;   // wrap: redundant, safe
        const u16* asC = As[bt];
        const u16* bsC = Bs[bt];
        u16* asN = As[bn];
        u16* bsN = Bs[bn];
        const int kN = ktn * 64;

        // ---- P1: need A0,B0(cur). read af0+bf0 (12). stage A0(next). m0xn01
        asm volatile("s_waitcnt vmcnt(4)" ::: "memory");
        __builtin_amdgcn_s_barrier();
        #pragma unroll
        for (int mr = 0; mr < 4; ++mr)
            #pragma unroll
            for (int ks = 0; ks < 2; ++ks)
                a_frag[mr * 2 + ks] = ldsfrag(asC, mr * 32 + wr16 + col, ks, quad);
        #pragma unroll
        for (int nr = 0; nr < 2; ++nr)
            #pragma unroll
            for (int ks = 0; ks < 2; ++ks)
                b_frag[nr * 2 + ks] = ldsfrag(bsC, nr * 64 + wc16 + col, ks, quad);
        stageA<AMODE>(asN, A, m0, kN, w, lane);
        asm volatile("s_waitcnt lgkmcnt(0)" ::: "memory");
        __builtin_amdgcn_sched_barrier(0);
        __builtin_amdgcn_s_setprio(1);
        #pragma unroll
        for (int mr = 0; mr < 4; ++mr)
            #pragma unroll
            for (int nr = 0; nr < 2; ++nr)
                #pragma unroll
                for (int ks = 0; ks < 2; ++ks)
                    acc[mr][nr] = mfma16(a_frag[mr * 2 + ks], b_frag[nr * 2 + ks], acc[mr][nr]);
        __builtin_amdgcn_s_setprio(0);

        // ---- P2: need B1(cur). read bf1 (4). stage B0(next). m0 x n23
        asm volatile("s_waitcnt vmcnt(4)" ::: "memory");
        __builtin_amdgcn_s_barrier();
        #pragma unroll
        for (int nr = 0; nr < 2; ++nr)
            #pragma unroll
            for (int ks = 0; ks < 2; ++ks)
                b_frag[nr * 2 + ks] = ldsfrag(bsC, (nr + 2) * 64 + wc16 + col, ks, quad);
        stageB256(bsN, Bt, n0, kN, w, lane);
        asm volatile("s_waitcnt lgkmcnt(0)" ::: "memory");
        __builtin_amdgcn_sched_barrier(0);
        __builtin_amdgcn_s_setprio(1);
        #pragma unroll
        for (int mr = 0; mr < 4; ++mr)
            #pragma unroll
            for (int nr = 0; nr < 2; ++nr)
                #pragma unroll
                for (int ks = 0; ks < 2; ++ks)
                    acc[mr][nr + 2] = mfma16(a_frag[mr * 2 + ks], b_frag[nr * 2 + ks], acc[mr][nr + 2]);
        __builtin_amdgcn_s_setprio(0);

        // ---- P3: need A1(cur). read af1 (8). stage B1(next). m47 x n23
        asm volatile("s_waitcnt vmcnt(4)" ::: "memory");
        __builtin_amdgcn_s_barrier();
        #pragma unroll
        for (int mr = 0; mr < 4; ++mr)
            #pragma unroll
            for (int ks = 0; ks < 2; ++ks)
                a_frag[mr * 2 + ks] = ldsfrag(asC, (mr + 4) * 32 + wr16 + col, ks, quad);
        stageB256(bsN + 128 * 64, Bt, n0 + 128, kN, w, lane);
        asm volatile("s_waitcnt lgkmcnt(0)" ::: "memory");
        __builtin_amdgcn_sched_barrier(0);
        __builtin_amdgcn_s_setprio(1);
        #pragma unroll
        for (int mr = 0; mr < 4; ++mr)
            #pragma unroll
            for (int nr = 0; nr < 2; ++nr)
                #pragma unroll
                for (int ks = 0; ks < 2; ++ks)
                    acc[mr + 4][nr + 2] = mfma16(a_frag[mr * 2 + ks], b_frag[nr * 2 + ks], acc[mr + 4][nr + 2]);
        __builtin_amdgcn_s_setprio(0);

        // ---- P4: B0(cur) already guaranteed at P1. re-read bf0 (4).
        //          stage A1(next). m47 x n01. No vmcnt (T4: never drain).
        __builtin_amdgcn_s_barrier();
        #pragma unroll
        for (int nr = 0; nr < 2; ++nr)
            #pragma unroll
            for (int ks = 0; ks < 2; ++ks)
                b_frag[nr * 2 + ks] = ldsfrag(bsC, nr * 64 + wc16 + col, ks, quad);
        stageA<AMODE>(asN + 128 * 64, A, m0 + 128, kN, w, lane);
        asm volatile("s_waitcnt lgkmcnt(0)" ::: "memory");
        __builtin_amdgcn_sched_barrier(0);
        __builtin_amdgcn_s_setprio(1);
        #pragma unroll
        for (int mr = 0; mr < 4; ++mr)
            #pragma unroll
            for (int nr = 0; nr < 2; ++nr)
                #pragma unroll
                for (int ks = 0; ks < 2; ++ks)
                    acc[mr + 4][nr] = mfma16(a_frag[mr * 2 + ks], b_frag[nr * 2 + ks], acc[mr + 4][nr]);
        __builtin_amdgcn_s_setprio(0);
    }

    // ---- epilogue: C write (same lane->element mapping as proven gemm_k)
    #pragma unroll
    for (int mr = 0; mr < 8; ++mr) {
        #pragma unroll
        for (int nr = 0; nr < 4; ++nr) {
            #pragma unroll
            for (int r = 0; r < 4; ++r) {
                int gm = m0 + mr * 32 + wr16 + quad * 4 + r;
                int gn = n0 + nr * 64 + wc16 + col;
                if constexpr (OMODE == 0) {
                    outf[(size_t)gm * N + gn] = acc[mr][nr][r];
                } else {   // OMODE == 3: QKV scatter
                    u16 bv = f2bf(acc[mr][nr][r]);
                    int b = gm >> 10, tq = gm & 1023;
                    int which = gn >> 11, rem = gn & 2047;
                    int hh = rem >> 7, d = rem & 127;
                    size_t bh = (size_t)b * 16 + hh;
                    if (which == 0)      Qo[(bh * 1024 + tq) * 128 + d] = bv;
                    else if (which == 1) Ko[(bh * 1024 + tq) * 128 + d] = bv;
                    else                 Vt[(bh * 128 + d) * 1024 + tq] = bv;
                }
            }
        }
    }
}

// ---------------------------------------------------------------------------
// Flash attention R8 (unchanged). Grid (T/64, H, B), 256 threads = 4 waves.
// ---------------------------------------------------------------------------
__global__ __launch_bounds__(256) void attn_kernel(
    u16* __restrict__ Q, const u16* __restrict__ K,
    const u16* __restrict__ VT) {
    __shared__ u16 Ks[64 * 128];     // swizzled, unpadded (async16 dst)
    __shared__ u16 Vs[128 * 64];     // swizzled, unpadded
    __shared__ u16 Ps[4][16][68];    // wave-private, padded (normal ds_write)

    const int qb = (int)(gridDim.x - 1) - (int)blockIdx.x;   // heavy first
    const int h = blockIdx.y, b = blockIdx.z;
    const int t = threadIdx.x;
    const int w = t >> 6, lane = t & 63;
    const int col = lane & 15, quad = lane >> 4;
    const int sw = col & 7;                       // read-side swizzle key
    const size_t bh = (size_t)b * 16 + h;
    u16* Qb = Q + bh * (1024 * 128);
    const u16* Kb = K + bh * (1024 * 128);
    const u16* Vb = VT + bh * (128 * 1024);
    const int q_lane = qb * 64 + w * 16 + col;

    // Q fragment, B-operand: lane holds Q[q=col][dh=kq*32+quad*8+j]
    bf16x8 qf[4];
    {
        const u16* qp = Qb + (size_t)q_lane * 128 + quad * 8;
        #pragma unroll
        for (int kq = 0; kq < 4; ++kq)
            qf[kq] = *(const bf16x8*)(qp + kq * 32);
    }

    f32x4 o[8];
    #pragma unroll
    for (int i = 0; i < 8; ++i) o[i] = (f32x4){0.f, 0.f, 0.f, 0.f};
    float m = NEG_BIG, l = 0.f;
    const float scale = 0.08838834764831845f;  // 1/sqrt(128)

    for (int kt = 0; kt <= qb; ++kt) {
        const u16* Kt = Kb + (size_t)kt * (64 * 128);

        // ---- stage K (64x128) + V^T (128x64) via swizzled async16 ----
        #pragma unroll
        for (int i = 0; i < 4; ++i) {
            int s = i * 256 + w * 64 + lane;          // chunk slot incl. lane
            int kr = s >> 4, kc = s & 15;             // K: 16 chunks/row
            async16(Kt + (size_t)kr * 128 + ((kc ^ (kr & 7)) << 3),
                    Ks + (size_t)(i * 256 + w * 64) * 8);
            int vr = s >> 3, vc = s & 7;              // V: 8 chunks/row
            async16(Vb + (size_t)vr * 1024 + kt * 64 + ((vc ^ (vr & 7)) << 3),
                    Vs + (size_t)(i * 256 + w * 64) * 8);
        }
        __syncthreads();

        // ---- S^T = K.Q^T ----
        const bool need_mask = (kt == qb);
        const int ttmax = need_mask ? w : 3;          // skip fully-masked strips
        f32x4 s[4];
        #pragma unroll
        for (int tt = 0; tt < 4; ++tt) {
            if (tt > ttmax) { s[tt] = (f32x4){NEG_BIG, NEG_BIG, NEG_BIG, NEG_BIG}; continue; }
            const u16* kbase = Ks + (size_t)(tt * 16 + col) * 128;
            f32x4 a = (f32x4){0.f, 0.f, 0.f, 0.f};
            #pragma unroll
            for (int kq = 0; kq < 4; ++kq)
                a = mfma16(*(const bf16x8*)(kbase + (((kq * 4 + quad) ^ sw) << 3)),
                           qf[kq], a);
            s[tt] = a;
        }

        // ---- scale + mask + max ----
        float rmax = NEG_BIG;
        #pragma unroll
        for (int tt = 0; tt < 4; ++tt) {
            if (tt > ttmax) continue;
            #pragma unroll
            for (int r = 0; r < 4; ++r) {
                float v = s[tt][r] * scale;
                int tg = kt * 64 + tt * 16 + quad * 4 + r;
                if (need_mask && tg > q_lane) v = NEG_BIG;
                s[tt][r] = v;
                rmax = fmaxf(rmax, v);
            }
        }
        rmax = fmaxf(rmax, __shfl_xor(rmax, 16, 64));
        rmax = fmaxf(rmax, __shfl_xor(rmax, 32, 64));

        float mnew = fmaxf(m, rmax);
        float alpha = __expf(m - mnew);
        m = mnew;

        // ---- P = exp(S^T - m) -> Ps[w][q][t] ----
        float rsum = 0.f;
        #pragma unroll
        for (int tt = 0; tt < 4; ++tt) {
            uint32_t* dst = (uint32_t*)&Ps[w][col][tt * 16 + quad * 4];
            if (tt > ttmax) { dst[0] = 0u; dst[1] = 0u; continue; }
            float p0 = __expf(s[tt][0] - mnew);
            float p1 = __expf(s[tt][1] - mnew);
            float p2 = __expf(s[tt][2] - mnew);
            float p3 = __expf(s[tt][3] - mnew);
            rsum += (p0 + p1) + (p2 + p3);
            dst[0] = pack2(p0, p1);
            dst[1] = pack2(p2, p3);
        }
        rsum += __shfl_xor(rsum, 16, 64);
        rsum += __shfl_xor(rsum, 32, 64);
        l = l * alpha + rsum;

        #pragma unroll
        for (int dt = 0; dt < 8; ++dt)
            #pragma unroll
            for (int r = 0; r < 4; ++r) o[dt][r] *= alpha;

        // ---- O^T += V^T.P^T ----
        #pragma unroll
        for (int ks = 0; ks < 2; ++ks) {
            bf16x8 pf = *(const bf16x8*)&Ps[w][col][ks * 32 + quad * 8];
            #pragma unroll
            for (int dt = 0; dt < 8; ++dt) {
                const u16* vbase = Vs + (size_t)(dt * 16 + col) * 64;
                o[dt] = mfma16(*(const bf16x8*)(vbase + (((ks * 4 + quad) ^ sw) << 3)),
                               pf, o[dt]);
            }
        }
        __syncthreads();   // all waves done reading before next overwrite
    }

    // epilogue: lane holds O^T[d=dt*16+quad*4+r][q=col]; 8B packed stores
    float inv = 1.0f / l;
    #pragma unroll
    for (int dt = 0; dt < 8; ++dt) {
        uint2 p;
        p.x = pack2(o[dt][0] * inv, o[dt][1] * inv);
        p.y = pack2(o[dt][2] * inv, o[dt][3] * inv);
        *(uint2*)&Qb[(size_t)q_lane * 128 + dt * 16 + quad * 4] = p;
    }
}

// ---------------------------------------------------------------------------
extern "C" void kernel_launch(void* const* d_in, const int* in_sizes, int n_in,
                              void* d_out, int out_size, void* d_ws, size_t ws_size,
                              hipStream_t stream) {
    const float* x      = (const float*)d_in[0];   // [4096, 2048]
    const float* w_qkv  = (const float*)d_in[1];   // [2048, 6144]
    const float* w_proj = (const float*)d_in[2];   // [2048, 2048]
    float* out = (float*)d_out;                    // [4096, 2048]

    const size_t SEG = (size_t)4 * 16 * 1024 * 128;      // 8,388,608 elems
    const size_t NEED_FAST = ((size_t)6144 * 2048 + SEG * 4) * 2;  // 92.3 MB

    if (ws_size >= NEED_FAST + (1u << 20)) {
        u16* wT = (u16*)d_ws;                 // 6144*2048, reused for proj
        u16* xb = wT + (size_t)6144 * 2048;
        u16* Qb = xb + SEG;
        u16* Kb = Qb + SEG;
        u16* Vb = Kb + SEG;

        cvt_bf16<<<4096, 256, 0, stream>>>(x, xb);
        transpose_w<<<dim3(96, 32), 256, 0, stream>>>(w_qkv, 6144, wT);

        gemm256<2, 3><<<dim3(24, 16), 512, 0, stream>>>(xb, wT, 6144,
                                                        nullptr, Qb, Kb, Vb);

        attn_kernel<<<dim3(16, 16, 4), 256, 0, stream>>>(Qb, Kb, Vb);

        transpose_w<<<dim3(32, 32), 256, 0, stream>>>(w_proj, 2048, wT);
        gemm256<1, 0><<<dim3(8, 16), 512, 0, stream>>>(Qb, wT, 2048,
                                                       out, nullptr, nullptr, nullptr);
    } else {
        // fallback (ws >= 58.7 MB), R5-proven sequence
        u16* wT = (u16*)d_ws;
        u16* Qb = wT + (size_t)2048 * 2048;
        u16* Kb = Qb + SEG;
        u16* Vb = Kb + SEG;

        transpose_w<<<dim3(32, 32), 256, 0, stream>>>(w_qkv + 0, 6144, wT);
        gemm_k<<<dim3(16, 32), 256, 0, stream>>>(x, wT, 2048, 0, 1,
                                                 nullptr, Qb, nullptr, nullptr);
        transpose_w<<<dim3(32, 32), 256, 0, stream>>>(w_qkv + 2048, 6144, wT);
        gemm_k<<<dim3(16, 32), 256, 0, stream>>>(x, wT, 2048, 0, 1,
                                                 nullptr, Kb, nullptr, nullptr);
        transpose_w<<<dim3(32, 32), 256, 0, stream>>>(w_qkv + 4096, 6144, wT);
        gemm_k<<<dim3(16, 32), 256, 0, stream>>>(x, wT, 2048, 0, 2,
                                                 nullptr, nullptr, nullptr, Vb);

        attn_kernel<<<dim3(16, 16, 4), 256, 0, stream>>>(Qb, Kb, Vb);

        transpose_w<<<dim3(32, 32), 256, 0, stream>>>(w_proj, 2048, wT);
        gemm_k<<<dim3(16, 32), 256, 0, stream>>>(Qb, wT, 2048, 3, 0,
                                                 out, nullptr, nullptr, nullptr);
    }
}

// Round 3
// 459.048 us; speedup vs baseline: 1.0385x; 1.0354x over previous
//
#include <hip/hip_runtime.h>
#include <cstdint>
#include <cstddef>

// Causal self-attention. fp32 in / fp32 out. bf16 MFMA compute, fp32 accum.
// B=4 T=1024 C=2048 H=16 Dh=128.
//
// R11: de-pin the 8-phase gemm256. R10 counters: bank-conflict 0 (swizzle
// works) but MfmaUtil 26% (m201: 62%) -> the per-phase lgkmcnt(0)+
// sched_barrier(0) pins (only required for inline-asm ds_reads, rule 18;
// m141: order-pinning = 874->510 TF) serialized {barrier, ds drain, MFMA}.
// Removed; compiler emits fine-grained lgkmcnt itself. B0 frags now cached
// in regs (P4 has 0 ds_reads). XCD swizzle on linear block id (T1).
// Proj reverted to gemm_k: gemm256 at 128 blocks left half the chip idle
// (rest-of-pipeline grew 292->308 us in R10).
//
// vmcnt ledger (2 loads per stage call, in-order retirement, m135):
// iter t stages tile t+1 in order P1:A0 P2:B0 P3:B1 P4:A1; consumption
// P1:{A0,B0} P2:{B1} P3:{A1} P4:{B0 cached}. vmcnt(4) at P1/P2/P3 retires
// exactly the half-tile needed; issued 3-4 phases prior (latency covered);
// never drains to 0 (T4).
//
// R8 attention unchanged.

typedef __attribute__((ext_vector_type(8))) __bf16 bf16x8;
typedef __attribute__((ext_vector_type(4))) float f32x4;
typedef unsigned short u16;

#define NEG_BIG (-1.0e30f)

__device__ __forceinline__ u16 f2bf(float f) {
    union { float f; uint32_t u; } v; v.f = f;
    uint32_t r = v.u + 0x7FFFu + ((v.u >> 16) & 1u);   // RNE
    return (u16)(r >> 16);
}

__device__ __forceinline__ uint32_t pack2(float a, float b) {
    return (uint32_t)f2bf(a) | ((uint32_t)f2bf(b) << 16);
}

__device__ __forceinline__ f32x4 mfma16(bf16x8 a, bf16x8 b, f32x4 c) {
    return __builtin_amdgcn_mfma_f32_16x16x32_bf16(a, b, c, 0, 0, 0);
}

// async global->LDS, 16B/lane; LDS dst = wave-uniform base (+lane*16 by HW)
__device__ __forceinline__ void async16(const u16* g, u16* l) {
    __builtin_amdgcn_global_load_lds(
        (const __attribute__((address_space(1))) void*)g,
        (__attribute__((address_space(3))) void*)l, 16, 0, 0);
}

// ---------------------------------------------------------------------------
__global__ __launch_bounds__(256) void cvt_bf16(
    const float* __restrict__ x, u16* __restrict__ xb) {
    size_t i = ((size_t)blockIdx.x * 256 + threadIdx.x) * 8;
    float4 u = *(const float4*)(x + i);
    float4 v = *(const float4*)(x + i + 4);
    uint4 p;
    p.x = pack2(u.x, u.y); p.y = pack2(u.z, u.w);
    p.z = pack2(v.x, v.y); p.w = pack2(v.z, v.w);
    *(uint4*)(xb + i) = p;
}

// ---------------------------------------------------------------------------
__global__ __launch_bounds__(256) void transpose_w(
    const float* __restrict__ W, int ldW, u16* __restrict__ WT) {
    __shared__ u16 tile[64][68];
    const int n0 = blockIdx.x * 64, k0 = blockIdx.y * 64;
    const int t = threadIdx.x;
    for (int i = t; i < 4096; i += 256) {
        int r = i >> 6, c = i & 63;
        tile[r][c] = f2bf(W[(size_t)(k0 + r) * ldW + n0 + c]);
    }
    __syncthreads();
    for (int i = t; i < 4096; i += 256) {
        int r = i >> 6, c = i & 63;
        WT[(size_t)(n0 + r) * 2048 + k0 + c] = tile[c][r];
    }
}

// ---------------------------------------------------------------------------
// 128x128 GEMM (R6-proven): used for proj (512 blocks, good occupancy) and
// the fallback path.
// ---------------------------------------------------------------------------
__global__ __launch_bounds__(256) void gemm_k(
    const void* __restrict__ Av, const u16* __restrict__ Bt,
    int N, int amode, int omode,
    float* __restrict__ outf, u16* __restrict__ Qo, u16* __restrict__ Ko,
    u16* __restrict__ Vt) {
    const int K = 2048;
    __shared__ u16 As[128][32];
    __shared__ u16 Bs[128][32];

    const float* A32 = (const float*)Av;
    const u16*   A16 = (const u16*)Av;

    const int m0 = blockIdx.y * 128, n0 = blockIdx.x * 128;
    const int t = threadIdx.x;
    const int w = t >> 6, lane = t & 63;
    const int col = lane & 15, quad = lane >> 4;
    const int wrow = (w >> 1) * 64, wcol = (w & 1) * 64;

    f32x4 acc[4][4];
    #pragma unroll
    for (int i = 0; i < 4; ++i)
        #pragma unroll
        for (int j = 0; j < 4; ++j)
            acc[i][j] = (f32x4){0.f, 0.f, 0.f, 0.f};

    u16* as_flat = &As[0][0];
    u16* bs_flat = &Bs[0][0];
    const int c1 = (w << 6) | lane;
    const int c2 = c1 + 256;

    for (int k0 = 0; k0 < K; k0 += 32) {
        {
            const u16* g1 = Bt + (size_t)(n0 + (c1 >> 2)) * K + k0 + ((c1 & 3) << 3);
            async16(g1, bs_flat + (size_t)w * 512);
            const u16* g2 = Bt + (size_t)(n0 + (c2 >> 2)) * K + k0 + ((c2 & 3) << 3);
            async16(g2, bs_flat + 2048 + (size_t)w * 512);
        }
        if (amode == 2) {
            const u16* g1 = A16 + (size_t)(m0 + (c1 >> 2)) * K + k0 + ((c1 & 3) << 3);
            async16(g1, as_flat + (size_t)w * 512);
            const u16* g2 = A16 + (size_t)(m0 + (c2 >> 2)) * K + k0 + ((c2 & 3) << 3);
            async16(g2, as_flat + 2048 + (size_t)w * 512);
        } else if (amode == 1) {
            #pragma unroll
            for (int cc = 0; cc < 2; ++cc) {
                int c = cc ? c2 : c1;
                int r = c >> 2, ko = (c & 3) << 3;
                int kg = k0 + ko, h = kg >> 7, d = kg & 127;
                int m = m0 + r, b = m >> 10, tt = m & 1023;
                const u16* g = A16 + (((size_t)(b * 16 + h)) * 1024 + tt) * 128 + d;
                async16(g, as_flat + (size_t)(cc ? 2048 : 0) + (size_t)w * 512);
            }
        } else if (amode == 0) {
            #pragma unroll
            for (int c = t; c < 512; c += 256) {
                int r = c >> 2, ko = (c & 3) * 8;
                size_t off = (size_t)(m0 + r) * K + k0 + ko;
                float4 u = *(const float4*)(A32 + off);
                float4 v = *(const float4*)(A32 + off + 4);
                uint4 p;
                p.x = pack2(u.x, u.y); p.y = pack2(u.z, u.w);
                p.z = pack2(v.x, v.y); p.w = pack2(v.z, v.w);
                *(uint4*)&As[r][ko] = p;
            }
        } else {
            #pragma unroll
            for (int c = t; c < 512; c += 256) {
                int r = c >> 2, ko = (c & 3) * 8;
                int kg = k0 + ko, h = kg >> 7, d = kg & 127;
                int m = m0 + r, b = m >> 10, tt = m & 1023;
                *(uint4*)&As[r][ko] =
                    *(const uint4*)(A16 + (((size_t)(b * 16 + h)) * 1024 + tt) * 128 + d);
            }
        }
        __syncthreads();

        bf16x8 afr[4], bfr[4];
        #pragma unroll
        for (int i = 0; i < 4; ++i)
            afr[i] = *(const bf16x8*)&As[wrow + i * 16 + col][quad * 8];
        #pragma unroll
        for (int i = 0; i < 4; ++i)
            bfr[i] = *(const bf16x8*)&Bs[wcol + i * 16 + col][quad * 8];

        #pragma unroll
        for (int mt = 0; mt < 4; ++mt)
            #pragma unroll
            for (int nt = 0; nt < 4; ++nt)
                acc[mt][nt] = mfma16(afr[mt], bfr[nt], acc[mt][nt]);
        __syncthreads();
    }

    #pragma unroll
    for (int mt = 0; mt < 4; ++mt) {
        #pragma unroll
        for (int nt = 0; nt < 4; ++nt) {
            #pragma unroll
            for (int r = 0; r < 4; ++r) {
                int gm = m0 + wrow + mt * 16 + quad * 4 + r;
                int gn = n0 + wcol + nt * 16 + col;
                if (omode == 0) {
                    outf[(size_t)gm * N + gn] = acc[mt][nt][r];
                } else {
                    u16 bv = f2bf(acc[mt][nt][r]);
                    int b = gm >> 10, tq = gm & 1023;
                    if (omode == 3) {
                        int which = gn >> 11, rem = gn & 2047;
                        int h = rem >> 7, d = rem & 127;
                        size_t bh = (size_t)b * 16 + h;
                        if (which == 0)      Qo[(bh * 1024 + tq) * 128 + d] = bv;
                        else if (which == 1) Ko[(bh * 1024 + tq) * 128 + d] = bv;
                        else                 Vt[(bh * 128 + d) * 1024 + tq] = bv;
                    } else {
                        int h = gn >> 7, d = gn & 127;
                        size_t bh = (size_t)b * 16 + h;
                        if (omode == 1) Qo[(bh * 1024 + tq) * 128 + d] = bv;
                        else            Vt[(bh * 128 + d) * 1024 + tq] = bv;
                    }
                }
            }
        }
    }
}

// ---------------------------------------------------------------------------
// R11 256x256 8-phase GEMM, de-pinned. 512 threads = 8 waves (2 wr x 4 wc),
// BK=64, double-buffered LDS (128 KiB). Swizzle: 16B chunk c of row r at
// chunk c^(r&7) (inverse-swizzled global src, linear LDS dst, XOR on read).
// Phase reads: P1:{A0,B0}=12 P2:{B1}=4 P3:{A1}=8 P4:{B0 cached in regs}=0.
// No lgkmcnt/sched_barrier pins (compiler-visible ds_reads; m97/m141).
// ---------------------------------------------------------------------------
__device__ __forceinline__ bf16x8 ldsfrag(const u16* buf, int row, int ksl, int quad) {
    return *(const bf16x8*)(buf + (size_t)row * 64 +
                            ((((ksl << 2) | quad) ^ (row & 7)) << 3));
}

template<int AMODE>
__device__ __forceinline__ void stageA(
    u16* halfb, const u16* A, int m0h, int k0, int w, int lane) {
    #pragma unroll
    for (int j = 0; j < 2; ++j) {
        int s0 = (j << 9) | (w << 6);
        int s = s0 + lane;
        int r = s >> 3;
        int gc = (s & 7) ^ (r & 7);
        int k = k0 + (gc << 3);
        const u16* src;
        if constexpr (AMODE == 2) {
            src = A + (size_t)(m0h + r) * 2048 + k;
        } else {
            int m = m0h + r, b = m >> 10, tt = m & 1023;
            int hh = k >> 7, d = k & 127;
            src = A + (((size_t)(b * 16 + hh)) * 1024 + tt) * 128 + d;
        }
        async16(src, halfb + (size_t)s0 * 8);
    }
}

__device__ __forceinline__ void stageB256(
    u16* halfb, const u16* Bt, int n0h, int k0, int w, int lane) {
    #pragma unroll
    for (int j = 0; j < 2; ++j) {
        int s0 = (j << 9) | (w << 6);
        int s = s0 + lane;
        int r = s >> 3;
        int gc = (s & 7) ^ (r & 7);
        async16(Bt + (size_t)(n0h + r) * 2048 + k0 + (gc << 3),
                halfb + (size_t)s0 * 8);
    }
}

template<int AMODE, int OMODE>
__global__ __launch_bounds__(512, 2) void gemm256(
    const u16* __restrict__ A, const u16* __restrict__ Bt, int N,
    float* __restrict__ outf, u16* __restrict__ Qo, u16* __restrict__ Ko,
    u16* __restrict__ Vt) {
    __shared__ u16 As[2][256 * 64];
    __shared__ u16 Bs[2][256 * 64];

    // T1: XCD-aware swizzle of linear block id (grids here are %8 == 0)
    const int nwg = (int)(gridDim.x * gridDim.y);
    const int lin = (int)(blockIdx.y * gridDim.x + blockIdx.x);
    const int cpx = nwg >> 3;
    const int swz = (lin & 7) * cpx + (lin >> 3);
    const int m0 = (swz / (int)gridDim.x) * 256;
    const int n0 = (swz % (int)gridDim.x) * 256;

    const int t = threadIdx.x;
    const int w = t >> 6, lane = t & 63;
    const int col = lane & 15, quad = lane >> 4;
    const int wr16 = ((w >> 2) & 1) << 4;   // 0 or 16
    const int wc16 = (w & 3) << 4;          // 0,16,32,48

    f32x4 acc[8][4];
    #pragma unroll
    for (int i = 0; i < 8; ++i)
        #pragma unroll
        for (int j = 0; j < 4; ++j)
            acc[i][j] = (f32x4){0.f, 0.f, 0.f, 0.f};

    // prologue: tile 0 -> buf0, issue order A0, B0, B1, A1
    stageA<AMODE>(As[0],             A,  m0,       0, w, lane);
    stageB256(    Bs[0],             Bt, n0,       0, w, lane);
    stageB256(    Bs[0] + 128 * 64,  Bt, n0 + 128, 0, w, lane);
    stageA<AMODE>(As[0] + 128 * 64,  A,  m0 + 128, 0, w, lane);

    const int NT = 2048 / 64;   // 32
    bf16x8 a_frag[8], b0_frag[4], b1_frag[4];

    for (int kt = 0; kt < NT; ++kt) {
        const int bt = kt & 1, bn = bt ^ 1;
        const int ktn = (kt + 1 < NT) ? kt + 1 : 0;   // wrap: redundant, safe
        const u16* asC = As[bt];
        const u16* bsC = Bs[bt];
        u16* asN = As[bn];
        u16* bsN = Bs[bn];
        const int kN = ktn * 64;

        // ---- P1: consume A0,B0(cur). reads 12. stage A0(next). m03 x n01
        asm volatile("s_waitcnt vmcnt(4)" ::: "memory");
        __builtin_amdgcn_s_barrier();
        #pragma unroll
        for (int mr = 0; mr < 4; ++mr)
            #pragma unroll
            for (int ks = 0; ks < 2; ++ks)
                a_frag[mr * 2 + ks] = ldsfrag(asC, mr * 32 + wr16 + col, ks, quad);
        #pragma unroll
        for (int nr = 0; nr < 2; ++nr)
            #pragma unroll
            for (int ks = 0; ks < 2; ++ks)
                b0_frag[nr * 2 + ks] = ldsfrag(bsC, nr * 64 + wc16 + col, ks, quad);
        stageA<AMODE>(asN, A, m0, kN, w, lane);
        __builtin_amdgcn_s_setprio(1);
        #pragma unroll
        for (int mr = 0; mr < 4; ++mr)
            #pragma unroll
            for (int nr = 0; nr < 2; ++nr)
                #pragma unroll
                for (int ks = 0; ks < 2; ++ks)
                    acc[mr][nr] = mfma16(a_frag[mr * 2 + ks], b0_frag[nr * 2 + ks], acc[mr][nr]);
        __builtin_amdgcn_s_setprio(0);

        // ---- P2: consume B1(cur). reads 4. stage B0(next). m03 x n23
        asm volatile("s_waitcnt vmcnt(4)" ::: "memory");
        __builtin_amdgcn_s_barrier();
        #pragma unroll
        for (int nr = 0; nr < 2; ++nr)
            #pragma unroll
            for (int ks = 0; ks < 2; ++ks)
                b1_frag[nr * 2 + ks] = ldsfrag(bsC, (nr + 2) * 64 + wc16 + col, ks, quad);
        stageB256(bsN, Bt, n0, kN, w, lane);
        __builtin_amdgcn_s_setprio(1);
        #pragma unroll
        for (int mr = 0; mr < 4; ++mr)
            #pragma unroll
            for (int nr = 0; nr < 2; ++nr)
                #pragma unroll
                for (int ks = 0; ks < 2; ++ks)
                    acc[mr][nr + 2] = mfma16(a_frag[mr * 2 + ks], b1_frag[nr * 2 + ks], acc[mr][nr + 2]);
        __builtin_amdgcn_s_setprio(0);

        // ---- P3: consume A1(cur). reads 8. stage B1(next). m47 x n23
        asm volatile("s_waitcnt vmcnt(4)" ::: "memory");
        __builtin_amdgcn_s_barrier();
        #pragma unroll
        for (int mr = 0; mr < 4; ++mr)
            #pragma unroll
            for (int ks = 0; ks < 2; ++ks)
                a_frag[mr * 2 + ks] = ldsfrag(asC, (mr + 4) * 32 + wr16 + col, ks, quad);
        stageB256(bsN + 128 * 64, Bt, n0 + 128, kN, w, lane);
        __builtin_amdgcn_s_setprio(1);
        #pragma unroll
        for (int mr = 0; mr < 4; ++mr)
            #pragma unroll
            for (int nr = 0; nr < 2; ++nr)
                #pragma unroll
                for (int ks = 0; ks < 2; ++ks)
                    acc[mr + 4][nr + 2] = mfma16(a_frag[mr * 2 + ks], b1_frag[nr * 2 + ks], acc[mr + 4][nr + 2]);
        __builtin_amdgcn_s_setprio(0);

        // ---- P4: B0 cached in regs -> 0 reads. stage A1(next). m47 x n01
        __builtin_amdgcn_s_barrier();
        stageA<AMODE>(asN + 128 * 64, A, m0 + 128, kN, w, lane);
        __builtin_amdgcn_s_setprio(1);
        #pragma unroll
        for (int mr = 0; mr < 4; ++mr)
            #pragma unroll
            for (int nr = 0; nr < 2; ++nr)
                #pragma unroll
                for (int ks = 0; ks < 2; ++ks)
                    acc[mr + 4][nr] = mfma16(a_frag[mr * 2 + ks], b0_frag[nr * 2 + ks], acc[mr + 4][nr]);
        __builtin_amdgcn_s_setprio(0);
    }

    // ---- epilogue: C write (same lane->element mapping as proven gemm_k)
    #pragma unroll
    for (int mr = 0; mr < 8; ++mr) {
        #pragma unroll
        for (int nr = 0; nr < 4; ++nr) {
            #pragma unroll
            for (int r = 0; r < 4; ++r) {
                int gm = m0 + mr * 32 + wr16 + quad * 4 + r;
                int gn = n0 + nr * 64 + wc16 + col;
                if constexpr (OMODE == 0) {
                    outf[(size_t)gm * N + gn] = acc[mr][nr][r];
                } else {   // OMODE == 3: QKV scatter
                    u16 bv = f2bf(acc[mr][nr][r]);
                    int b = gm >> 10, tq = gm & 1023;
                    int which = gn >> 11, rem = gn & 2047;
                    int hh = rem >> 7, d = rem & 127;
                    size_t bh = (size_t)b * 16 + hh;
                    if (which == 0)      Qo[(bh * 1024 + tq) * 128 + d] = bv;
                    else if (which == 1) Ko[(bh * 1024 + tq) * 128 + d] = bv;
                    else                 Vt[(bh * 128 + d) * 1024 + tq] = bv;
                }
            }
        }
    }
}

// ---------------------------------------------------------------------------
// Flash attention R8 (unchanged). Grid (T/64, H, B), 256 threads = 4 waves.
// ---------------------------------------------------------------------------
__global__ __launch_bounds__(256) void attn_kernel(
    u16* __restrict__ Q, const u16* __restrict__ K,
    const u16* __restrict__ VT) {
    __shared__ u16 Ks[64 * 128];     // swizzled, unpadded (async16 dst)
    __shared__ u16 Vs[128 * 64];     // swizzled, unpadded
    __shared__ u16 Ps[4][16][68];    // wave-private, padded (normal ds_write)

    const int qb = (int)(gridDim.x - 1) - (int)blockIdx.x;   // heavy first
    const int h = blockIdx.y, b = blockIdx.z;
    const int t = threadIdx.x;
    const int w = t >> 6, lane = t & 63;
    const int col = lane & 15, quad = lane >> 4;
    const int sw = col & 7;                       // read-side swizzle key
    const size_t bh = (size_t)b * 16 + h;
    u16* Qb = Q + bh * (1024 * 128);
    const u16* Kb = K + bh * (1024 * 128);
    const u16* Vb = VT + bh * (128 * 1024);
    const int q_lane = qb * 64 + w * 16 + col;

    // Q fragment, B-operand: lane holds Q[q=col][dh=kq*32+quad*8+j]
    bf16x8 qf[4];
    {
        const u16* qp = Qb + (size_t)q_lane * 128 + quad * 8;
        #pragma unroll
        for (int kq = 0; kq < 4; ++kq)
            qf[kq] = *(const bf16x8*)(qp + kq * 32);
    }

    f32x4 o[8];
    #pragma unroll
    for (int i = 0; i < 8; ++i) o[i] = (f32x4){0.f, 0.f, 0.f, 0.f};
    float m = NEG_BIG, l = 0.f;
    const float scale = 0.08838834764831845f;  // 1/sqrt(128)

    for (int kt = 0; kt <= qb; ++kt) {
        const u16* Kt = Kb + (size_t)kt * (64 * 128);

        // ---- stage K (64x128) + V^T (128x64) via swizzled async16 ----
        #pragma unroll
        for (int i = 0; i < 4; ++i) {
            int s = i * 256 + w * 64 + lane;          // chunk slot incl. lane
            int kr = s >> 4, kc = s & 15;             // K: 16 chunks/row
            async16(Kt + (size_t)kr * 128 + ((kc ^ (kr & 7)) << 3),
                    Ks + (size_t)(i * 256 + w * 64) * 8);
            int vr = s >> 3, vc = s & 7;              // V: 8 chunks/row
            async16(Vb + (size_t)vr * 1024 + kt * 64 + ((vc ^ (vr & 7)) << 3),
                    Vs + (size_t)(i * 256 + w * 64) * 8);
        }
        __syncthreads();

        // ---- S^T = K.Q^T ----
        const bool need_mask = (kt == qb);
        const int ttmax = need_mask ? w : 3;          // skip fully-masked strips
        f32x4 s[4];
        #pragma unroll
        for (int tt = 0; tt < 4; ++tt) {
            if (tt > ttmax) { s[tt] = (f32x4){NEG_BIG, NEG_BIG, NEG_BIG, NEG_BIG}; continue; }
            const u16* kbase = Ks + (size_t)(tt * 16 + col) * 128;
            f32x4 a = (f32x4){0.f, 0.f, 0.f, 0.f};
            #pragma unroll
            for (int kq = 0; kq < 4; ++kq)
                a = mfma16(*(const bf16x8*)(kbase + (((kq * 4 + quad) ^ sw) << 3)),
                           qf[kq], a);
            s[tt] = a;
        }

        // ---- scale + mask + max ----
        float rmax = NEG_BIG;
        #pragma unroll
        for (int tt = 0; tt < 4; ++tt) {
            if (tt > ttmax) continue;
            #pragma unroll
            for (int r = 0; r < 4; ++r) {
                float v = s[tt][r] * scale;
                int tg = kt * 64 + tt * 16 + quad * 4 + r;
                if (need_mask && tg > q_lane) v = NEG_BIG;
                s[tt][r] = v;
                rmax = fmaxf(rmax, v);
            }
        }
        rmax = fmaxf(rmax, __shfl_xor(rmax, 16, 64));
        rmax = fmaxf(rmax, __shfl_xor(rmax, 32, 64));

        float mnew = fmaxf(m, rmax);
        float alpha = __expf(m - mnew);
        m = mnew;

        // ---- P = exp(S^T - m) -> Ps[w][q][t] ----
        float rsum = 0.f;
        #pragma unroll
        for (int tt = 0; tt < 4; ++tt) {
            uint32_t* dst = (uint32_t*)&Ps[w][col][tt * 16 + quad * 4];
            if (tt > ttmax) { dst[0] = 0u; dst[1] = 0u; continue; }
            float p0 = __expf(s[tt][0] - mnew);
            float p1 = __expf(s[tt][1] - mnew);
            float p2 = __expf(s[tt][2] - mnew);
            float p3 = __expf(s[tt][3] - mnew);
            rsum += (p0 + p1) + (p2 + p3);
            dst[0] = pack2(p0, p1);
            dst[1] = pack2(p2, p3);
        }
        rsum += __shfl_xor(rsum, 16, 64);
        rsum += __shfl_xor(rsum, 32, 64);
        l = l * alpha + rsum;

        #pragma unroll
        for (int dt = 0; dt < 8; ++dt)
            #pragma unroll
            for (int r = 0; r < 4; ++r) o[dt][r] *= alpha;

        // ---- O^T += V^T.P^T ----
        #pragma unroll
        for (int ks = 0; ks < 2; ++ks) {
            bf16x8 pf = *(const bf16x8*)&Ps[w][col][ks * 32 + quad * 8];
            #pragma unroll
            for (int dt = 0; dt < 8; ++dt) {
                const u16* vbase = Vs + (size_t)(dt * 16 + col) * 64;
                o[dt] = mfma16(*(const bf16x8*)(vbase + (((ks * 4 + quad) ^ sw) << 3)),
                               pf, o[dt]);
            }
        }
        __syncthreads();   // all waves done reading before next overwrite
    }

    // epilogue: lane holds O^T[d=dt*16+quad*4+r][q=col]; 8B packed stores
    float inv = 1.0f / l;
    #pragma unroll
    for (int dt = 0; dt < 8; ++dt) {
        uint2 p;
        p.x = pack2(o[dt][0] * inv, o[dt][1] * inv);
        p.y = pack2(o[dt][2] * inv, o[dt][3] * inv);
        *(uint2*)&Qb[(size_t)q_lane * 128 + dt * 16 + quad * 4] = p;
    }
}

// ---------------------------------------------------------------------------
extern "C" void kernel_launch(void* const* d_in, const int* in_sizes, int n_in,
                              void* d_out, int out_size, void* d_ws, size_t ws_size,
                              hipStream_t stream) {
    const float* x      = (const float*)d_in[0];   // [4096, 2048]
    const float* w_qkv  = (const float*)d_in[1];   // [2048, 6144]
    const float* w_proj = (const float*)d_in[2];   // [2048, 2048]
    float* out = (float*)d_out;                    // [4096, 2048]

    const size_t SEG = (size_t)4 * 16 * 1024 * 128;      // 8,388,608 elems
    const size_t NEED_FAST = ((size_t)6144 * 2048 + SEG * 4) * 2;  // 92.3 MB

    if (ws_size >= NEED_FAST + (1u << 20)) {
        u16* wT = (u16*)d_ws;                 // 6144*2048, reused for proj
        u16* xb = wT + (size_t)6144 * 2048;
        u16* Qb = xb + SEG;
        u16* Kb = Qb + SEG;
        u16* Vb = Kb + SEG;

        cvt_bf16<<<4096, 256, 0, stream>>>(x, xb);
        transpose_w<<<dim3(96, 32), 256, 0, stream>>>(w_qkv, 6144, wT);

        gemm256<2, 3><<<dim3(24, 16), 512, 0, stream>>>(xb, wT, 6144,
                                                        nullptr, Qb, Kb, Vb);

        attn_kernel<<<dim3(16, 16, 4), 256, 0, stream>>>(Qb, Kb, Vb);

        transpose_w<<<dim3(32, 32), 256, 0, stream>>>(w_proj, 2048, wT);
        gemm_k<<<dim3(16, 32), 256, 0, stream>>>(Qb, wT, 2048, 1, 0,
                                                 out, nullptr, nullptr, nullptr);
    } else {
        // fallback (ws >= 58.7 MB), R5-proven sequence
        u16* wT = (u16*)d_ws;
        u16* Qb = wT + (size_t)2048 * 2048;
        u16* Kb = Qb + SEG;
        u16* Vb = Kb + SEG;

        transpose_w<<<dim3(32, 32), 256, 0, stream>>>(w_qkv + 0, 6144, wT);
        gemm_k<<<dim3(16, 32), 256, 0, stream>>>(x, wT, 2048, 0, 1,
                                                 nullptr, Qb, nullptr, nullptr);
        transpose_w<<<dim3(32, 32), 256, 0, stream>>>(w_qkv + 2048, 6144, wT);
        gemm_k<<<dim3(16, 32), 256, 0, stream>>>(x, wT, 2048, 0, 1,
                                                 nullptr, Kb, nullptr, nullptr);
        transpose_w<<<dim3(32, 32), 256, 0, stream>>>(w_qkv + 4096, 6144, wT);
        gemm_k<<<dim3(16, 32), 256, 0, stream>>>(x, wT, 2048, 0, 2,
                                                 nullptr, nullptr, nullptr, Vb);

        attn_kernel<<<dim3(16, 16, 4), 256, 0, stream>>>(Qb, Kb, Vb);

        transpose_w<<<dim3(32, 32), 256, 0, stream>>>(w_proj, 2048, wT);
        gemm_k<<<dim3(16, 32), 256, 0, stream>>>(Qb, wT, 2048, 3, 0,
                                                 out, nullptr, nullptr, nullptr);
    }
}

// Round 4
// 437.809 us; speedup vs baseline: 1.0888x; 1.0485x over previous
//
#include <hip/hip_runtime.h>
#include <cstdint>
#include <cstddef>

// Causal self-attention. fp32 in / fp32 out. bf16 MFMA compute, fp32 accum.
// B=4 T=1024 C=2048 H=16 Dh=128.
//
// R12: (a) remove XCD swizzle from gemm256 -- R11 FETCH doubled 97->182 MB
// (each XCD streamed all B panels; L3-fit regime, m160: swizzle negative).
// (b) m201-faithful phase ordering: ds_reads hoisted ABOVE the opening
// barrier so they overlap the previous phase's MFMA drain; counted vmcnt
// ledger re-derived: stage-then-vmcnt(4) at B1/B2/B4, none at B3; every
// retired half-tile was staged >=2 phases earlier; never drains to 0.
// Phase consumption {A0,B0}/{B1}/{A1}/{B0 cached}; stage order A0,B0,B1,A1
// into the opposite buffer (distance-1 prefetch, no WAR with cur reads).
//
// R8 attention + R6 gemm_k (proj) unchanged.

typedef __attribute__((ext_vector_type(8))) __bf16 bf16x8;
typedef __attribute__((ext_vector_type(4))) float f32x4;
typedef unsigned short u16;

#define NEG_BIG (-1.0e30f)

__device__ __forceinline__ u16 f2bf(float f) {
    union { float f; uint32_t u; } v; v.f = f;
    uint32_t r = v.u + 0x7FFFu + ((v.u >> 16) & 1u);   // RNE
    return (u16)(r >> 16);
}

__device__ __forceinline__ uint32_t pack2(float a, float b) {
    return (uint32_t)f2bf(a) | ((uint32_t)f2bf(b) << 16);
}

__device__ __forceinline__ f32x4 mfma16(bf16x8 a, bf16x8 b, f32x4 c) {
    return __builtin_amdgcn_mfma_f32_16x16x32_bf16(a, b, c, 0, 0, 0);
}

// async global->LDS, 16B/lane; LDS dst = wave-uniform base (+lane*16 by HW)
__device__ __forceinline__ void async16(const u16* g, u16* l) {
    __builtin_amdgcn_global_load_lds(
        (const __attribute__((address_space(1))) void*)g,
        (__attribute__((address_space(3))) void*)l, 16, 0, 0);
}

// ---------------------------------------------------------------------------
__global__ __launch_bounds__(256) void cvt_bf16(
    const float* __restrict__ x, u16* __restrict__ xb) {
    size_t i = ((size_t)blockIdx.x * 256 + threadIdx.x) * 8;
    float4 u = *(const float4*)(x + i);
    float4 v = *(const float4*)(x + i + 4);
    uint4 p;
    p.x = pack2(u.x, u.y); p.y = pack2(u.z, u.w);
    p.z = pack2(v.x, v.y); p.w = pack2(v.z, v.w);
    *(uint4*)(xb + i) = p;
}

// ---------------------------------------------------------------------------
__global__ __launch_bounds__(256) void transpose_w(
    const float* __restrict__ W, int ldW, u16* __restrict__ WT) {
    __shared__ u16 tile[64][68];
    const int n0 = blockIdx.x * 64, k0 = blockIdx.y * 64;
    const int t = threadIdx.x;
    for (int i = t; i < 4096; i += 256) {
        int r = i >> 6, c = i & 63;
        tile[r][c] = f2bf(W[(size_t)(k0 + r) * ldW + n0 + c]);
    }
    __syncthreads();
    for (int i = t; i < 4096; i += 256) {
        int r = i >> 6, c = i & 63;
        WT[(size_t)(n0 + r) * 2048 + k0 + c] = tile[c][r];
    }
}

// ---------------------------------------------------------------------------
// 128x128 GEMM (R6-proven): used for proj (512 blocks, good occupancy) and
// the fallback path.
// ---------------------------------------------------------------------------
__global__ __launch_bounds__(256) void gemm_k(
    const void* __restrict__ Av, const u16* __restrict__ Bt,
    int N, int amode, int omode,
    float* __restrict__ outf, u16* __restrict__ Qo, u16* __restrict__ Ko,
    u16* __restrict__ Vt) {
    const int K = 2048;
    __shared__ u16 As[128][32];
    __shared__ u16 Bs[128][32];

    const float* A32 = (const float*)Av;
    const u16*   A16 = (const u16*)Av;

    const int m0 = blockIdx.y * 128, n0 = blockIdx.x * 128;
    const int t = threadIdx.x;
    const int w = t >> 6, lane = t & 63;
    const int col = lane & 15, quad = lane >> 4;
    const int wrow = (w >> 1) * 64, wcol = (w & 1) * 64;

    f32x4 acc[4][4];
    #pragma unroll
    for (int i = 0; i < 4; ++i)
        #pragma unroll
        for (int j = 0; j < 4; ++j)
            acc[i][j] = (f32x4){0.f, 0.f, 0.f, 0.f};

    u16* as_flat = &As[0][0];
    u16* bs_flat = &Bs[0][0];
    const int c1 = (w << 6) | lane;
    const int c2 = c1 + 256;

    for (int k0 = 0; k0 < K; k0 += 32) {
        {
            const u16* g1 = Bt + (size_t)(n0 + (c1 >> 2)) * K + k0 + ((c1 & 3) << 3);
            async16(g1, bs_flat + (size_t)w * 512);
            const u16* g2 = Bt + (size_t)(n0 + (c2 >> 2)) * K + k0 + ((c2 & 3) << 3);
            async16(g2, bs_flat + 2048 + (size_t)w * 512);
        }
        if (amode == 2) {
            const u16* g1 = A16 + (size_t)(m0 + (c1 >> 2)) * K + k0 + ((c1 & 3) << 3);
            async16(g1, as_flat + (size_t)w * 512);
            const u16* g2 = A16 + (size_t)(m0 + (c2 >> 2)) * K + k0 + ((c2 & 3) << 3);
            async16(g2, as_flat + 2048 + (size_t)w * 512);
        } else if (amode == 1) {
            #pragma unroll
            for (int cc = 0; cc < 2; ++cc) {
                int c = cc ? c2 : c1;
                int r = c >> 2, ko = (c & 3) << 3;
                int kg = k0 + ko, h = kg >> 7, d = kg & 127;
                int m = m0 + r, b = m >> 10, tt = m & 1023;
                const u16* g = A16 + (((size_t)(b * 16 + h)) * 1024 + tt) * 128 + d;
                async16(g, as_flat + (size_t)(cc ? 2048 : 0) + (size_t)w * 512);
            }
        } else if (amode == 0) {
            #pragma unroll
            for (int c = t; c < 512; c += 256) {
                int r = c >> 2, ko = (c & 3) * 8;
                size_t off = (size_t)(m0 + r) * K + k0 + ko;
                float4 u = *(const float4*)(A32 + off);
                float4 v = *(const float4*)(A32 + off + 4);
                uint4 p;
                p.x = pack2(u.x, u.y); p.y = pack2(u.z, u.w);
                p.z = pack2(v.x, v.y); p.w = pack2(v.z, v.w);
                *(uint4*)&As[r][ko] = p;
            }
        } else {
            #pragma unroll
            for (int c = t; c < 512; c += 256) {
                int r = c >> 2, ko = (c & 3) * 8;
                int kg = k0 + ko, h = kg >> 7, d = kg & 127;
                int m = m0 + r, b = m >> 10, tt = m & 1023;
                *(uint4*)&As[r][ko] =
                    *(const uint4*)(A16 + (((size_t)(b * 16 + h)) * 1024 + tt) * 128 + d);
            }
        }
        __syncthreads();

        bf16x8 afr[4], bfr[4];
        #pragma unroll
        for (int i = 0; i < 4; ++i)
            afr[i] = *(const bf16x8*)&As[wrow + i * 16 + col][quad * 8];
        #pragma unroll
        for (int i = 0; i < 4; ++i)
            bfr[i] = *(const bf16x8*)&Bs[wcol + i * 16 + col][quad * 8];

        #pragma unroll
        for (int mt = 0; mt < 4; ++mt)
            #pragma unroll
            for (int nt = 0; nt < 4; ++nt)
                acc[mt][nt] = mfma16(afr[mt], bfr[nt], acc[mt][nt]);
        __syncthreads();
    }

    #pragma unroll
    for (int mt = 0; mt < 4; ++mt) {
        #pragma unroll
        for (int nt = 0; nt < 4; ++nt) {
            #pragma unroll
            for (int r = 0; r < 4; ++r) {
                int gm = m0 + wrow + mt * 16 + quad * 4 + r;
                int gn = n0 + wcol + nt * 16 + col;
                if (omode == 0) {
                    outf[(size_t)gm * N + gn] = acc[mt][nt][r];
                } else {
                    u16 bv = f2bf(acc[mt][nt][r]);
                    int b = gm >> 10, tq = gm & 1023;
                    if (omode == 3) {
                        int which = gn >> 11, rem = gn & 2047;
                        int h = rem >> 7, d = rem & 127;
                        size_t bh = (size_t)b * 16 + h;
                        if (which == 0)      Qo[(bh * 1024 + tq) * 128 + d] = bv;
                        else if (which == 1) Ko[(bh * 1024 + tq) * 128 + d] = bv;
                        else                 Vt[(bh * 128 + d) * 1024 + tq] = bv;
                    } else {
                        int h = gn >> 7, d = gn & 127;
                        size_t bh = (size_t)b * 16 + h;
                        if (omode == 1) Qo[(bh * 1024 + tq) * 128 + d] = bv;
                        else            Vt[(bh * 128 + d) * 1024 + tq] = bv;
                    }
                }
            }
        }
    }
}

// ---------------------------------------------------------------------------
// R12 256x256 8-phase GEMM. 512 threads = 8 waves (2 wr x 4 wc), BK=64,
// double-buffered LDS (128 KiB). Linear block ids (no XCD swizzle).
// Per boundary: {pre-barrier ds_reads; stage; vmcnt; s_barrier; 16 MFMA}.
// vmcnt ledger (2 loads/stage, stage-then-wait, in-order retirement):
//   entering B1: out=[B1(t),A1(t)]=4
//   B1: +A0(t+1)=6, vmcnt(4) retires B1(t)       -> reads B1(t) legal at B2
//   B2: +B0(t+1)=6, vmcnt(4) retires A1(t)       -> reads A1(t) legal at B3
//   B3: +B1(t+1)=6, no wait
//   B4: +A1(t+1)=8, vmcnt(4) retires A0,B0(t+1)  -> reads at next B1 legal
// Every retired load staged >=2 phases (~600cy) earlier; never drains to 0.
// ---------------------------------------------------------------------------
__device__ __forceinline__ bf16x8 ldsfrag(const u16* buf, int row, int ksl, int quad) {
    return *(const bf16x8*)(buf + (size_t)row * 64 +
                            ((((ksl << 2) | quad) ^ (row & 7)) << 3));
}

template<int AMODE>
__device__ __forceinline__ void stageA(
    u16* halfb, const u16* A, int m0h, int k0, int w, int lane) {
    #pragma unroll
    for (int j = 0; j < 2; ++j) {
        int s0 = (j << 9) | (w << 6);
        int s = s0 + lane;
        int r = s >> 3;
        int gc = (s & 7) ^ (r & 7);
        int k = k0 + (gc << 3);
        const u16* src;
        if constexpr (AMODE == 2) {
            src = A + (size_t)(m0h + r) * 2048 + k;
        } else {
            int m = m0h + r, b = m >> 10, tt = m & 1023;
            int hh = k >> 7, d = k & 127;
            src = A + (((size_t)(b * 16 + hh)) * 1024 + tt) * 128 + d;
        }
        async16(src, halfb + (size_t)s0 * 8);
    }
}

__device__ __forceinline__ void stageB256(
    u16* halfb, const u16* Bt, int n0h, int k0, int w, int lane) {
    #pragma unroll
    for (int j = 0; j < 2; ++j) {
        int s0 = (j << 9) | (w << 6);
        int s = s0 + lane;
        int r = s >> 3;
        int gc = (s & 7) ^ (r & 7);
        async16(Bt + (size_t)(n0h + r) * 2048 + k0 + (gc << 3),
                halfb + (size_t)s0 * 8);
    }
}

template<int AMODE, int OMODE>
__global__ __launch_bounds__(512, 2) void gemm256(
    const u16* __restrict__ A, const u16* __restrict__ Bt, int N,
    float* __restrict__ outf, u16* __restrict__ Qo, u16* __restrict__ Ko,
    u16* __restrict__ Vt) {
    __shared__ u16 As[2][256 * 64];
    __shared__ u16 Bs[2][256 * 64];

    const int m0 = blockIdx.y * 256, n0 = blockIdx.x * 256;
    const int t = threadIdx.x;
    const int w = t >> 6, lane = t & 63;
    const int col = lane & 15, quad = lane >> 4;
    const int wr16 = ((w >> 2) & 1) << 4;   // 0 or 16
    const int wc16 = (w & 3) << 4;          // 0,16,32,48

    f32x4 acc[8][4];
    #pragma unroll
    for (int i = 0; i < 8; ++i)
        #pragma unroll
        for (int j = 0; j < 4; ++j)
            acc[i][j] = (f32x4){0.f, 0.f, 0.f, 0.f};

    // prologue: tile 0 -> buf0 in order A0, B0, B1, A1; retire A0,B0; barrier
    stageA<AMODE>(As[0],             A,  m0,       0, w, lane);
    stageB256(    Bs[0],             Bt, n0,       0, w, lane);
    stageB256(    Bs[0] + 128 * 64,  Bt, n0 + 128, 0, w, lane);
    stageA<AMODE>(As[0] + 128 * 64,  A,  m0 + 128, 0, w, lane);
    asm volatile("s_waitcnt vmcnt(4)" ::: "memory");
    __builtin_amdgcn_s_barrier();

    const int NT = 2048 / 64;   // 32
    bf16x8 a_frag[8], b0_frag[4], b1_frag[4];

    for (int kt = 0; kt < NT; ++kt) {
        const int bt = kt & 1, bn = bt ^ 1;
        const int ktn = (kt + 1 < NT) ? kt + 1 : 0;   // wrap: redundant, safe
        const u16* asC = As[bt];
        const u16* bsC = Bs[bt];
        u16* asN = As[bn];
        u16* bsN = Bs[bn];
        const int kN = ktn * 64;

        // ---- B1: reads A0c,B0c (guaranteed at prev B4); stage A0n;
        //          vmcnt(4) retires B1c; barrier; MFMA m03 x n01
        #pragma unroll
        for (int mr = 0; mr < 4; ++mr)
            #pragma unroll
            for (int ks = 0; ks < 2; ++ks)
                a_frag[mr * 2 + ks] = ldsfrag(asC, mr * 32 + wr16 + col, ks, quad);
        #pragma unroll
        for (int nr = 0; nr < 2; ++nr)
            #pragma unroll
            for (int ks = 0; ks < 2; ++ks)
                b0_frag[nr * 2 + ks] = ldsfrag(bsC, nr * 64 + wc16 + col, ks, quad);
        stageA<AMODE>(asN, A, m0, kN, w, lane);
        asm volatile("s_waitcnt vmcnt(4)" ::: "memory");
        __builtin_amdgcn_s_barrier();
        __builtin_amdgcn_s_setprio(1);
        #pragma unroll
        for (int mr = 0; mr < 4; ++mr)
            #pragma unroll
            for (int nr = 0; nr < 2; ++nr)
                #pragma unroll
                for (int ks = 0; ks < 2; ++ks)
                    acc[mr][nr] = mfma16(a_frag[mr * 2 + ks], b0_frag[nr * 2 + ks], acc[mr][nr]);
        __builtin_amdgcn_s_setprio(0);

        // ---- B2: reads B1c (guaranteed at B1); stage B0n;
        //          vmcnt(4) retires A1c; barrier; MFMA m03 x n23
        #pragma unroll
        for (int nr = 0; nr < 2; ++nr)
            #pragma unroll
            for (int ks = 0; ks < 2; ++ks)
                b1_frag[nr * 2 + ks] = ldsfrag(bsC, (nr + 2) * 64 + wc16 + col, ks, quad);
        stageB256(bsN, Bt, n0, kN, w, lane);
        asm volatile("s_waitcnt vmcnt(4)" ::: "memory");
        __builtin_amdgcn_s_barrier();
        __builtin_amdgcn_s_setprio(1);
        #pragma unroll
        for (int mr = 0; mr < 4; ++mr)
            #pragma unroll
            for (int nr = 0; nr < 2; ++nr)
                #pragma unroll
                for (int ks = 0; ks < 2; ++ks)
                    acc[mr][nr + 2] = mfma16(a_frag[mr * 2 + ks], b1_frag[nr * 2 + ks], acc[mr][nr + 2]);
        __builtin_amdgcn_s_setprio(0);

        // ---- B3: reads A1c (guaranteed at B2); stage B1n; barrier;
        //          MFMA m47 x n23
        #pragma unroll
        for (int mr = 0; mr < 4; ++mr)
            #pragma unroll
            for (int ks = 0; ks < 2; ++ks)
                a_frag[mr * 2 + ks] = ldsfrag(asC, (mr + 4) * 32 + wr16 + col, ks, quad);
        stageB256(bsN + 128 * 64, Bt, n0 + 128, kN, w, lane);
        __builtin_amdgcn_s_barrier();
        __builtin_amdgcn_s_setprio(1);
        #pragma unroll
        for (int mr = 0; mr < 4; ++mr)
            #pragma unroll
            for (int nr = 0; nr < 2; ++nr)
                #pragma unroll
                for (int ks = 0; ks < 2; ++ks)
                    acc[mr + 4][nr + 2] = mfma16(a_frag[mr * 2 + ks], b1_frag[nr * 2 + ks], acc[mr + 4][nr + 2]);
        __builtin_amdgcn_s_setprio(0);

        // ---- B4: no reads (b0 cached); stage A1n; vmcnt(4) retires A0n,B0n
        //          (guarantees next iter's B1 reads); barrier; MFMA m47 x n01
        stageA<AMODE>(asN + 128 * 64, A, m0 + 128, kN, w, lane);
        asm volatile("s_waitcnt vmcnt(4)" ::: "memory");
        __builtin_amdgcn_s_barrier();
        __builtin_amdgcn_s_setprio(1);
        #pragma unroll
        for (int mr = 0; mr < 4; ++mr)
            #pragma unroll
            for (int nr = 0; nr < 2; ++nr)
                #pragma unroll
                for (int ks = 0; ks < 2; ++ks)
                    acc[mr + 4][nr] = mfma16(a_frag[mr * 2 + ks], b0_frag[nr * 2 + ks], acc[mr + 4][nr]);
        __builtin_amdgcn_s_setprio(0);
    }

    // ---- epilogue: C write (same lane->element mapping as proven gemm_k)
    #pragma unroll
    for (int mr = 0; mr < 8; ++mr) {
        #pragma unroll
        for (int nr = 0; nr < 4; ++nr) {
            #pragma unroll
            for (int r = 0; r < 4; ++r) {
                int gm = m0 + mr * 32 + wr16 + quad * 4 + r;
                int gn = n0 + nr * 64 + wc16 + col;
                if constexpr (OMODE == 0) {
                    outf[(size_t)gm * N + gn] = acc[mr][nr][r];
                } else {   // OMODE == 3: QKV scatter
                    u16 bv = f2bf(acc[mr][nr][r]);
                    int b = gm >> 10, tq = gm & 1023;
                    int which = gn >> 11, rem = gn & 2047;
                    int hh = rem >> 7, d = rem & 127;
                    size_t bh = (size_t)b * 16 + hh;
                    if (which == 0)      Qo[(bh * 1024 + tq) * 128 + d] = bv;
                    else if (which == 1) Ko[(bh * 1024 + tq) * 128 + d] = bv;
                    else                 Vt[(bh * 128 + d) * 1024 + tq] = bv;
                }
            }
        }
    }
}

// ---------------------------------------------------------------------------
// Flash attention R8 (unchanged). Grid (T/64, H, B), 256 threads = 4 waves.
// ---------------------------------------------------------------------------
__global__ __launch_bounds__(256) void attn_kernel(
    u16* __restrict__ Q, const u16* __restrict__ K,
    const u16* __restrict__ VT) {
    __shared__ u16 Ks[64 * 128];     // swizzled, unpadded (async16 dst)
    __shared__ u16 Vs[128 * 64];     // swizzled, unpadded
    __shared__ u16 Ps[4][16][68];    // wave-private, padded (normal ds_write)

    const int qb = (int)(gridDim.x - 1) - (int)blockIdx.x;   // heavy first
    const int h = blockIdx.y, b = blockIdx.z;
    const int t = threadIdx.x;
    const int w = t >> 6, lane = t & 63;
    const int col = lane & 15, quad = lane >> 4;
    const int sw = col & 7;                       // read-side swizzle key
    const size_t bh = (size_t)b * 16 + h;
    u16* Qb = Q + bh * (1024 * 128);
    const u16* Kb = K + bh * (1024 * 128);
    const u16* Vb = VT + bh * (128 * 1024);
    const int q_lane = qb * 64 + w * 16 + col;

    // Q fragment, B-operand: lane holds Q[q=col][dh=kq*32+quad*8+j]
    bf16x8 qf[4];
    {
        const u16* qp = Qb + (size_t)q_lane * 128 + quad * 8;
        #pragma unroll
        for (int kq = 0; kq < 4; ++kq)
            qf[kq] = *(const bf16x8*)(qp + kq * 32);
    }

    f32x4 o[8];
    #pragma unroll
    for (int i = 0; i < 8; ++i) o[i] = (f32x4){0.f, 0.f, 0.f, 0.f};
    float m = NEG_BIG, l = 0.f;
    const float scale = 0.08838834764831845f;  // 1/sqrt(128)

    for (int kt = 0; kt <= qb; ++kt) {
        const u16* Kt = Kb + (size_t)kt * (64 * 128);

        // ---- stage K (64x128) + V^T (128x64) via swizzled async16 ----
        #pragma unroll
        for (int i = 0; i < 4; ++i) {
            int s = i * 256 + w * 64 + lane;          // chunk slot incl. lane
            int kr = s >> 4, kc = s & 15;             // K: 16 chunks/row
            async16(Kt + (size_t)kr * 128 + ((kc ^ (kr & 7)) << 3),
                    Ks + (size_t)(i * 256 + w * 64) * 8);
            int vr = s >> 3, vc = s & 7;              // V: 8 chunks/row
            async16(Vb + (size_t)vr * 1024 + kt * 64 + ((vc ^ (vr & 7)) << 3),
                    Vs + (size_t)(i * 256 + w * 64) * 8);
        }
        __syncthreads();

        // ---- S^T = K.Q^T ----
        const bool need_mask = (kt == qb);
        const int ttmax = need_mask ? w : 3;          // skip fully-masked strips
        f32x4 s[4];
        #pragma unroll
        for (int tt = 0; tt < 4; ++tt) {
            if (tt > ttmax) { s[tt] = (f32x4){NEG_BIG, NEG_BIG, NEG_BIG, NEG_BIG}; continue; }
            const u16* kbase = Ks + (size_t)(tt * 16 + col) * 128;
            f32x4 a = (f32x4){0.f, 0.f, 0.f, 0.f};
            #pragma unroll
            for (int kq = 0; kq < 4; ++kq)
                a = mfma16(*(const bf16x8*)(kbase + (((kq * 4 + quad) ^ sw) << 3)),
                           qf[kq], a);
            s[tt] = a;
        }

        // ---- scale + mask + max ----
        float rmax = NEG_BIG;
        #pragma unroll
        for (int tt = 0; tt < 4; ++tt) {
            if (tt > ttmax) continue;
            #pragma unroll
            for (int r = 0; r < 4; ++r) {
                float v = s[tt][r] * scale;
                int tg = kt * 64 + tt * 16 + quad * 4 + r;
                if (need_mask && tg > q_lane) v = NEG_BIG;
                s[tt][r] = v;
                rmax = fmaxf(rmax, v);
            }
        }
        rmax = fmaxf(rmax, __shfl_xor(rmax, 16, 64));
        rmax = fmaxf(rmax, __shfl_xor(rmax, 32, 64));

        float mnew = fmaxf(m, rmax);
        float alpha = __expf(m - mnew);
        m = mnew;

        // ---- P = exp(S^T - m) -> Ps[w][q][t] ----
        float rsum = 0.f;
        #pragma unroll
        for (int tt = 0; tt < 4; ++tt) {
            uint32_t* dst = (uint32_t*)&Ps[w][col][tt * 16 + quad * 4];
            if (tt > ttmax) { dst[0] = 0u; dst[1] = 0u; continue; }
            float p0 = __expf(s[tt][0] - mnew);
            float p1 = __expf(s[tt][1] - mnew);
            float p2 = __expf(s[tt][2] - mnew);
            float p3 = __expf(s[tt][3] - mnew);
            rsum += (p0 + p1) + (p2 + p3);
            dst[0] = pack2(p0, p1);
            dst[1] = pack2(p2, p3);
        }
        rsum += __shfl_xor(rsum, 16, 64);
        rsum += __shfl_xor(rsum, 32, 64);
        l = l * alpha + rsum;

        #pragma unroll
        for (int dt = 0; dt < 8; ++dt)
            #pragma unroll
            for (int r = 0; r < 4; ++r) o[dt][r] *= alpha;

        // ---- O^T += V^T.P^T ----
        #pragma unroll
        for (int ks = 0; ks < 2; ++ks) {
            bf16x8 pf = *(const bf16x8*)&Ps[w][col][ks * 32 + quad * 8];
            #pragma unroll
            for (int dt = 0; dt < 8; ++dt) {
                const u16* vbase = Vs + (size_t)(dt * 16 + col) * 64;
                o[dt] = mfma16(*(const bf16x8*)(vbase + (((ks * 4 + quad) ^ sw) << 3)),
                               pf, o[dt]);
            }
        }
        __syncthreads();   // all waves done reading before next overwrite
    }

    // epilogue: lane holds O^T[d=dt*16+quad*4+r][q=col]; 8B packed stores
    float inv = 1.0f / l;
    #pragma unroll
    for (int dt = 0; dt < 8; ++dt) {
        uint2 p;
        p.x = pack2(o[dt][0] * inv, o[dt][1] * inv);
        p.y = pack2(o[dt][2] * inv, o[dt][3] * inv);
        *(uint2*)&Qb[(size_t)q_lane * 128 + dt * 16 + quad * 4] = p;
    }
}

// ---------------------------------------------------------------------------
extern "C" void kernel_launch(void* const* d_in, const int* in_sizes, int n_in,
                              void* d_out, int out_size, void* d_ws, size_t ws_size,
                              hipStream_t stream) {
    const float* x      = (const float*)d_in[0];   // [4096, 2048]
    const float* w_qkv  = (const float*)d_in[1];   // [2048, 6144]
    const float* w_proj = (const float*)d_in[2];   // [2048, 2048]
    float* out = (float*)d_out;                    // [4096, 2048]

    const size_t SEG = (size_t)4 * 16 * 1024 * 128;      // 8,388,608 elems
    const size_t NEED_FAST = ((size_t)6144 * 2048 + SEG * 4) * 2;  // 92.3 MB

    if (ws_size >= NEED_FAST + (1u << 20)) {
        u16* wT = (u16*)d_ws;                 // 6144*2048, reused for proj
        u16* xb = wT + (size_t)6144 * 2048;
        u16* Qb = xb + SEG;
        u16* Kb = Qb + SEG;
        u16* Vb = Kb + SEG;

        cvt_bf16<<<4096, 256, 0, stream>>>(x, xb);
        transpose_w<<<dim3(96, 32), 256, 0, stream>>>(w_qkv, 6144, wT);

        gemm256<2, 3><<<dim3(24, 16), 512, 0, stream>>>(xb, wT, 6144,
                                                        nullptr, Qb, Kb, Vb);

        attn_kernel<<<dim3(16, 16, 4), 256, 0, stream>>>(Qb, Kb, Vb);

        transpose_w<<<dim3(32, 32), 256, 0, stream>>>(w_proj, 2048, wT);
        gemm_k<<<dim3(16, 32), 256, 0, stream>>>(Qb, wT, 2048, 1, 0,
                                                 out, nullptr, nullptr, nullptr);
    } else {
        // fallback (ws >= 58.7 MB), R5-proven sequence
        u16* wT = (u16*)d_ws;
        u16* Qb = wT + (size_t)2048 * 2048;
        u16* Kb = Qb + SEG;
        u16* Vb = Kb + SEG;

        transpose_w<<<dim3(32, 32), 256, 0, stream>>>(w_qkv + 0, 6144, wT);
        gemm_k<<<dim3(16, 32), 256, 0, stream>>>(x, wT, 2048, 0, 1,
                                                 nullptr, Qb, nullptr, nullptr);
        transpose_w<<<dim3(32, 32), 256, 0, stream>>>(w_qkv + 2048, 6144, wT);
        gemm_k<<<dim3(16, 32), 256, 0, stream>>>(x, wT, 2048, 0, 1,
                                                 nullptr, Kb, nullptr, nullptr);
        transpose_w<<<dim3(32, 32), 256, 0, stream>>>(w_qkv + 4096, 6144, wT);
        gemm_k<<<dim3(16, 32), 256, 0, stream>>>(x, wT, 2048, 0, 2,
                                                 nullptr, nullptr, nullptr, Vb);

        attn_kernel<<<dim3(16, 16, 4), 256, 0, stream>>>(Qb, Kb, Vb);

        transpose_w<<<dim3(32, 32), 256, 0, stream>>>(w_proj, 2048, wT);
        gemm_k<<<dim3(16, 32), 256, 0, stream>>>(Qb, wT, 2048, 3, 0,
                                                 out, nullptr, nullptr, nullptr);
    }
}